// Round 11
// baseline (296.747 us; speedup 1.0000x reference)
//
#include <hip/hip_runtime.h>

#define NN 50000
#define NE 800000
#define FD 128
#define FDH 64            // FD/2 packed bf16 pairs
#define FA 32
#define NG 128
#define EETOT (NE + NN)
#define NBLK ((NN + 255) / 256)   // 196 scan tiles
#define NPXCD 6250                // nodes per XCD-parity bin
#define ECHK 2048                 // edges per bin chunk
#define NCHK ((NE + ECHK - 1) / ECHK)   // 391 chunks
#define FPB 52                    // fill block-groups per parity
#define FILLB (8 * FPB)           // 416 fill blocks
#define GEMMB ((NN + 63) / 64)    // 782 gemm blocks

typedef __attribute__((ext_vector_type(8))) short short8;
typedef __attribute__((ext_vector_type(4))) float f32x4;

// ---------- bf16 helpers ----------
__device__ __forceinline__ float bfbits(unsigned short u) {
    return __uint_as_float(((unsigned int)u) << 16);
}
__device__ __forceinline__ float bflo(unsigned int p) { return __uint_as_float(p << 16); }
__device__ __forceinline__ float bfhi(unsigned int p) { return __uint_as_float(p & 0xffff0000u); }
__device__ __forceinline__ unsigned short f2bf(float f) {   // RNE
    unsigned int u = __float_as_uint(f);
    unsigned int r = u + 0x7FFFu + ((u >> 16) & 1u);
    return (unsigned short)(r >> 16);
}
__device__ __forceinline__ unsigned int packbf(float a, float b) {
    return (unsigned int)f2bf(a) | ((unsigned int)f2bf(b) << 16);
}

// ---------- inline wave-parallel dtype probes ----------
__device__ __forceinline__ int wave_probe_bf16(const unsigned int* t, int nwords) {
    int lane = threadIdx.x & 63;
    unsigned int wv = (lane < nwords) ? t[lane] : 0u;
    int nzp = (wv != 0u) ? 1 : 0;
    unsigned int e = (wv >> 7) & 0xFFu;
    int hitp = (nzp && e >= 100u && e <= 140u) ? 1 : 0;
    int nz = __popcll(__ballot(nzp));
    int hits = __popcll(__ballot(hitp));
    return (nz < 8) ? 1 : (hits * 4 >= nz * 3);
}
__device__ __forceinline__ int wave_probe_is64(const int* ei) {
    int lane = threadIdx.x & 63;
    int v = (lane < 32) ? ei[2 * lane + 1] : 0;
    return (__ballot(v != 0) == 0ull) ? 1 : 0;
}

// ---------- sentinels ----------
__global__ __launch_bounds__(128) void mark_kernel(float* out, float v) {
    out[threadIdx.x] = v;
}

// ---------- prep: weights + params + zero {degi,tsum} (round-8 proven) ----------
__global__ __launch_bounds__(256) void prep(
        const void* addf, const void* w1, const void* b1, const void* w2,
        const void* b2, const void* fc1w, const void* fc1b, const void* fc2w,
        const void* fc2b, unsigned int* W1t, unsigned int* W2t,
        float* addff, float* b1f, float* b2f, float* fc1wf, float* fc1bf,
        float* fc2wf, float* fc2bf, int* degi, int* tsum) {
    int b = blockIdx.x;
    if (b < 64) {
        int rel = b * 256 + threadIdx.x;             // [0,16384)
        const void* src = (rel < 8192) ? w1 : w2;
        unsigned int* dst = (rel < 8192) ? W1t : W2t;
        int flag = wave_probe_bf16((const unsigned int*)src, 64);
        int rr = rel & 8191;
        int n = rr >> 6, kk = rr & 63;
        float lo, hi;
        if (flag) {
            const unsigned short* s = (const unsigned short*)src;
            lo = bfbits(s[(2 * kk) * FD + n]);
            hi = bfbits(s[(2 * kk + 1) * FD + n]);
        } else {
            const float* s = (const float*)src;
            lo = s[(2 * kk) * FD + n];
            hi = s[(2 * kk + 1) * FD + n];
        }
        dst[rr] = packbf(lo, hi);
    } else if (b < 163) {
        int i = (b - 64) * 256 + threadIdx.x;        // [0,25344)
        int wb = (b - 64) * 256 + (threadIdx.x & ~63);  // wave base
        const void* src; float* dst; int base; int prnw; int lim;
        if      (wb < 4096)  { src = addf; dst = addff; base = 0;     prnw = 64; lim = 4096;  }
        else if (wb < 4224)  { src = b1;   dst = b1f;   base = 4096;  prnw = 64; lim = 128;   }
        else if (wb < 4352)  { src = b2;   dst = b2f;   base = 4224;  prnw = 64; lim = 128;   }
        else if (wb < 24832) { src = fc1w; dst = fc1wf; base = 4352;  prnw = 64; lim = 20480; }
        else if (wb < 24960) { src = fc1b; dst = fc1bf; base = 24832; prnw = 64; lim = 128;   }
        else if (wb < 25216) { src = fc2w; dst = fc2wf; base = 24960; prnw = 64; lim = 256;   }
        else if (wb < 25280) { src = fc2b; dst = fc2bf; base = 25216; prnw = 1;  lim = 2;     }
        else return;
        int flag = wave_probe_bf16((const unsigned int*)src, prnw);
        int rel = i - base;
        if (rel < lim) {
            if (flag) dst[rel] = bfbits(((const unsigned short*)src)[rel]);
            else      dst[rel] = ((const float*)src)[rel];
        }
    } else {
        int i = (b - 163) * 256 + threadIdx.x;
        if      (i < NN)       degi[i] = 0;
        else if (i < NN + 256) tsum[i - NN] = 0;
    }
}

// ---------- degree + chunk-local parity binning (round-8 proven) ----------
__global__ __launch_bounds__(256) void bin_kernel(const int* ei, int* deg,
        int2* ebsd, int* bofs) {
    __shared__ int cnt[8];
    __shared__ int sbase[8];
    int is64 = wave_probe_is64(ei);
    int chunk = blockIdx.x;
    int e0 = chunk * ECHK;
    int nedge = NE - e0; if (nedge > ECHK) nedge = ECHK;
    if (threadIdx.x < 8) cnt[threadIdx.x] = 0;
    __syncthreads();
    int sA[8], dA[8], rk[8], pr[8];
    #pragma unroll
    for (int k = 0; k < 8; ++k) {
        int j = k * 256 + threadIdx.x;
        pr[k] = -1;
        if (j < nedge) {
            int e = e0 + j;
            int s = is64 ? ei[2 * e] : ei[e];
            int d = is64 ? ei[2 * (NE + e)] : ei[NE + e];
            atomicAdd(&deg[d], 1);          // spread over 50K addrs: cheap
            int p = d / NPXCD;
            sA[k] = s; dA[k] = d; pr[k] = p;
            rk[k] = atomicAdd(&cnt[p], 1);  // LDS atomic: on-CU, fast
        }
    }
    __syncthreads();
    if (threadIdx.x == 0) {
        int acc = 0;
        #pragma unroll
        for (int p = 0; p < 8; ++p) {
            sbase[p] = acc;
            bofs[chunk * 8 + p] = acc;
            acc += cnt[p];
        }
    }
    __syncthreads();
    #pragma unroll
    for (int k = 0; k < 8; ++k) {
        if (pr[k] >= 0) {
            int idx = chunk * ECHK + sbase[pr[k]] + rk[k];
            ebsd[idx] = make_int2(sA[k], dA[k]);
        }
    }
}

// ---------- merged: fused scan (blocks < NBLK) + GEMM1 (blocks >= NBLK) ----------
// scan needs bin's degi; gemm1 needs prep's W1t + input x — independent halves.
// Deadlock-safe: 196 scan blocks < 256 CUs even at 1 block/CU; gemm blocks
// always complete so slots always free up for un-dispatched scan blocks.
__global__ __launch_bounds__(256) void scan_gemm1(const int* degi, const int* batch,
        int* tsum, float* dinv, int* rowstart, int* cursor, int* gstart,
        const void* __restrict__ Av, const unsigned int* __restrict__ Wt,
        unsigned short* __restrict__ C) {
    if ((int)blockIdx.x < NBLK) {
        __shared__ int sh[256];
        int b = blockIdx.x, t = threadIdx.x;
        int i = b * 256 + t;
        int d = (i < NN) ? degi[i] : 0;
        if (i < NN) dinv[i] = rsqrtf((float)(d + 1));
        int v = (i < NN) ? d + 1 : 0;
        sh[t] = v;
        __syncthreads();
        for (int off = 1; off < 256; off <<= 1) {
            int a = (t >= off) ? sh[t - off] : 0;
            __syncthreads();
            sh[t] += a;
            __syncthreads();
        }
        int incl = sh[t];
        int total = sh[255];
        if (t == 0) atomicExch(&tsum[b], total);   // publish first; total >= 80 > 0
        int pt = 0;
        for (int j = t; j < b; j += 256) {
            int s;
            do { s = atomicAdd(&tsum[j], 0); } while (s == 0);
            pt += s;
        }
        __syncthreads();
        sh[t] = pt;
        __syncthreads();
        for (int off = 128; off >= 1; off >>= 1) {
            if (t < off) sh[t] += sh[t + off];
            __syncthreads();
        }
        int boff = sh[0];
        if (i < NN) {
            int r = boff + incl - v;
            rowstart[i] = r;
            cursor[i]   = r;
        }
        if (i == 0) rowstart[NN] = EETOT;
        if (i < NN) {
            int is64 = (batch[NN - 1] == 0) ? 1 : 0;
            int bc = is64 ? batch[2 * i] : batch[i];
            if (i == 0) {
                for (int g = 0; g <= bc; ++g) gstart[g] = 0;
            } else {
                int bp = is64 ? batch[2 * (i - 1)] : batch[i - 1];
                for (int g = bp + 1; g <= bc; ++g) gstart[g] = i;
            }
            if (i == NN - 1) {
                for (int g = bc + 1; g <= NG; ++g) gstart[g] = NN;
            }
        }
        return;
    }
    // ---- gemm1: C[NN][128] = toBF16(A) @ W1t, A possibly fp32 ----
    int bid = blockIdx.x - NBLK;
    int wave = threadIdx.x >> 6;
    int lane = threadIdx.x & 63;
    int quad = lane >> 4;
    int l16  = lane & 15;
    int mbase = bid * 64 + wave * 16;
    int ra = mbase + l16;
    if (ra >= NN) ra = NN - 1;
    bool f32in = !wave_probe_bf16((const unsigned int*)Av, 64);
    short8 af[4];
    if (!f32in) {
        const uint4* Arow = (const uint4*)((const unsigned int*)Av + (size_t)ra * FDH);
        #pragma unroll
        for (int kk = 0; kk < 4; ++kk) {
            uint4 v = Arow[kk * 4 + quad];
            af[kk] = *(short8*)&v;
        }
    } else {
        const float* Arow = (const float*)Av + (size_t)ra * FD;
        #pragma unroll
        for (int kk = 0; kk < 4; ++kk) {
            const float4* p = (const float4*)(Arow + (kk * 4 + quad) * 8);
            float4 u = p[0], v = p[1];
            uint4 q;
            q.x = packbf(u.x, u.y); q.y = packbf(u.z, u.w);
            q.z = packbf(v.x, v.y); q.w = packbf(v.z, v.w);
            af[kk] = *(short8*)&q;
        }
    }
    #pragma unroll
    for (int nt = 0; nt < 8; ++nt) {
        int n = nt * 16 + l16;
        const uint4* Wrow = (const uint4*)(Wt + (size_t)n * FDH);
        f32x4 acc = {0.f, 0.f, 0.f, 0.f};
        #pragma unroll
        for (int kk = 0; kk < 4; ++kk) {
            uint4 wv = Wrow[kk * 4 + quad];
            short8 bf = *(short8*)&wv;
            acc = __builtin_amdgcn_mfma_f32_16x16x32_bf16(af[kk], bf, acc, 0, 0, 0);
        }
        int row0 = mbase + quad * 4;
        #pragma unroll
        for (int reg = 0; reg < 4; ++reg) {
            int r = row0 + reg;
            if (r < NN) C[(size_t)r * FD + nt * 16 + l16] = f2bf(acc[reg]);
        }
    }
}

// ---------- binned CSR fill (standalone: cv lines stay L2-resident) ----------
__global__ __launch_bounds__(256) void fill_kernel(const int2* ebsd, const int* bofs,
        const float* dinv, int* cursor, unsigned int* cv) {
    int par = blockIdx.x & 7;        // matches XCD round-robin
    int g   = blockIdx.x >> 3;       // group within parity [0,FPB)
    for (int chunk = g; chunk < NCHK; chunk += FPB) {
        int b0 = bofs[chunk * 8 + par];
        int nedge = NE - chunk * ECHK; if (nedge > ECHK) nedge = ECHK;
        int b1 = (par < 7) ? bofs[chunk * 8 + par + 1] : nedge;
        for (int j = b0 + (int)threadIdx.x; j < b1; j += 256) {
            int2 sd = ebsd[chunk * ECHK + j];
            int pos = atomicAdd(&cursor[sd.y], 1);
            cv[pos] = (unsigned int)sd.x
                    | ((unsigned int)f2bf(dinv[sd.x] * dinv[sd.y]) << 16);
        }
    }
    // self-loops for this parity's node range
    for (int n = par * NPXCD + g * 256 + threadIdx.x; n < (par + 1) * NPXCD;
         n += FPB * 256) {
        int pos = atomicAdd(&cursor[n], 1);
        float di = dinv[n];
        cv[pos] = (unsigned int)n | ((unsigned int)f2bf(di * di) << 16);
    }
}

// ---------- standalone MFMA GEMM (layer 2, bf16 input) ----------
__global__ __launch_bounds__(256) void gemm_mfma(const unsigned int* __restrict__ Av,
        const unsigned int* __restrict__ Wt, unsigned short* __restrict__ C) {
    int wave = threadIdx.x >> 6;
    int lane = threadIdx.x & 63;
    int quad = lane >> 4;
    int l16  = lane & 15;
    int mbase = blockIdx.x * 64 + wave * 16;
    int ra = mbase + l16;
    if (ra >= NN) ra = NN - 1;
    short8 af[4];
    const uint4* Arow = (const uint4*)(Av + (size_t)ra * FDH);
    #pragma unroll
    for (int kk = 0; kk < 4; ++kk) {
        uint4 v = Arow[kk * 4 + quad];
        af[kk] = *(short8*)&v;
    }
    #pragma unroll
    for (int nt = 0; nt < 8; ++nt) {
        int n = nt * 16 + l16;
        const uint4* Wrow = (const uint4*)(Wt + (size_t)n * FDH);
        f32x4 acc = {0.f, 0.f, 0.f, 0.f};
        #pragma unroll
        for (int kk = 0; kk < 4; ++kk) {
            uint4 wv = Wrow[kk * 4 + quad];
            short8 bf = *(short8*)&wv;
            acc = __builtin_amdgcn_mfma_f32_16x16x32_bf16(af[kk], bf, acc, 0, 0, 0);
        }
        int row0 = mbase + quad * 4;
        #pragma unroll
        for (int reg = 0; reg < 4; ++reg) {
            int r = row0 + reg;
            if (r < NN) C[(size_t)r * FD + nt * 16 + l16] = f2bf(acc[reg]);
        }
    }
}

// ---------- CSR aggregation: uint4 gathers, 4 rows/wave, 16 rows/block ----------
__global__ __launch_bounds__(256) void aggregate_kernel(const unsigned int* Hb,
        const unsigned int* cv, const int* rowstart, const float* bias,
        unsigned int* outb) {
    int lane = threadIdx.x & 63;
    int r4   = lane >> 4;            // row within wave 0..3
    int c4   = lane & 15;            // uint4 index within 64-word row
    int wv   = threadIdx.x >> 6;
    int n = blockIdx.x * 16 + wv * 4 + r4;   // NN % 16 == 0
    const uint4* H4 = (const uint4*)Hb;
    int jb = rowstart[n], je = rowstart[n + 1];
    float a0 = 0.f, a1 = 0.f, a2 = 0.f, a3 = 0.f;
    float a4 = 0.f, a5 = 0.f, a6 = 0.f, a7 = 0.f;
    int j = jb;
    for (; j + 7 < je; j += 8) {
        unsigned int rr[8]; uint4 hh[8];
        #pragma unroll
        for (int k = 0; k < 8; ++k) rr[k] = cv[j + k];
        #pragma unroll
        for (int k = 0; k < 8; ++k) hh[k] = H4[(size_t)(rr[k] & 0xFFFFu) * 16 + c4];
        #pragma unroll
        for (int k = 0; k < 8; ++k) {
            float v = bfbits((unsigned short)(rr[k] >> 16));
            a0 += v * bflo(hh[k].x); a1 += v * bfhi(hh[k].x);
            a2 += v * bflo(hh[k].y); a3 += v * bfhi(hh[k].y);
            a4 += v * bflo(hh[k].z); a5 += v * bfhi(hh[k].z);
            a6 += v * bflo(hh[k].w); a7 += v * bfhi(hh[k].w);
        }
    }
    for (; j + 3 < je; j += 4) {
        unsigned int rr[4]; uint4 hh[4];
        #pragma unroll
        for (int k = 0; k < 4; ++k) rr[k] = cv[j + k];
        #pragma unroll
        for (int k = 0; k < 4; ++k) hh[k] = H4[(size_t)(rr[k] & 0xFFFFu) * 16 + c4];
        #pragma unroll
        for (int k = 0; k < 4; ++k) {
            float v = bfbits((unsigned short)(rr[k] >> 16));
            a0 += v * bflo(hh[k].x); a1 += v * bfhi(hh[k].x);
            a2 += v * bflo(hh[k].y); a3 += v * bfhi(hh[k].y);
            a4 += v * bflo(hh[k].z); a5 += v * bfhi(hh[k].z);
            a6 += v * bflo(hh[k].w); a7 += v * bfhi(hh[k].w);
        }
    }
    for (; j < je; ++j) {
        unsigned int r = cv[j];
        uint4 h = H4[(size_t)(r & 0xFFFFu) * 16 + c4];
        float v = bfbits((unsigned short)(r >> 16));
        a0 += v * bflo(h.x); a1 += v * bfhi(h.x);
        a2 += v * bflo(h.y); a3 += v * bfhi(h.y);
        a4 += v * bflo(h.z); a5 += v * bfhi(h.z);
        a6 += v * bflo(h.w); a7 += v * bfhi(h.w);
    }
    a0 = fmaxf(a0 + bias[8 * c4 + 0], 0.f);
    a1 = fmaxf(a1 + bias[8 * c4 + 1], 0.f);
    a2 = fmaxf(a2 + bias[8 * c4 + 2], 0.f);
    a3 = fmaxf(a3 + bias[8 * c4 + 3], 0.f);
    a4 = fmaxf(a4 + bias[8 * c4 + 4], 0.f);
    a5 = fmaxf(a5 + bias[8 * c4 + 5], 0.f);
    a6 = fmaxf(a6 + bias[8 * c4 + 6], 0.f);
    a7 = fmaxf(a7 + bias[8 * c4 + 7], 0.f);
    uint4 out;
    out.x = packbf(a0, a1);
    out.y = packbf(a2, a3);
    out.z = packbf(a4, a5);
    out.w = packbf(a6, a7);
    ((uint4*)outb)[(size_t)n * 16 + c4] = out;
}

// ---------- fused mean-pool + MLP head ----------
__global__ __launch_bounds__(256) void poolhead(const unsigned int* Hb,
        const int* gstart, const float* addf, const float* fc1w, const float* fc1b,
        const float* fc2w, const float* fc2b, const unsigned int* x, void* outp) {
    int g = blockIdx.x;
    int t = threadIdx.x;
    int q = t >> 6, w = t & 63;
    int obf = wave_probe_bf16(x, 64);
    int s = gstart[g], e = gstart[g + 1];
    float a0 = 0.f, a1 = 0.f;
    #pragma unroll 4
    for (int n = s + q; n < e; n += 4) {
        unsigned int h = Hb[(size_t)n * FDH + w];
        a0 += bflo(h);
        a1 += bfhi(h);
    }
    __shared__ float pp[4][FD];
    __shared__ float z[FD + FA];
    __shared__ float h[FD];
    pp[q][2 * w]     = a0;
    pp[q][2 * w + 1] = a1;
    __syncthreads();
    if (t < FD) {
        float cnt = (float)(e - s);
        if (cnt < 1.0f) cnt = 1.0f;
        z[t] = (pp[0][t] + pp[1][t] + pp[2][t] + pp[3][t]) / cnt;
    }
    if (t >= FD && t < FD + FA) z[t] = addf[g * FA + (t - FD)];
    __syncthreads();
    if (t < FD) {
        float acc = fc1b[t];
        #pragma unroll 4
        for (int k = 0; k < FD + FA; ++k)
            acc += z[k] * fc1w[k * FD + t];
        h[t] = fmaxf(acc, 0.f);
    }
    __syncthreads();
    if (t < 2) {
        float o = fc2b[t];
        for (int j = 0; j < FD; ++j) o += h[j] * fc2w[j * 2 + t];
        if (obf) ((unsigned short*)outp)[g * 2 + t] = f2bf(o);
        else     ((float*)outp)[g * 2 + t] = o;
    }
}

extern "C" void kernel_launch(void* const* d_in, const int* in_sizes, int n_in,
                              void* d_out, int out_size, void* d_ws, size_t ws_size,
                              hipStream_t stream) {
    (void)out_size;

    if (n_in != 12) {
        hipLaunchKernelGGL(mark_kernel, dim3(1), dim3(128), 0, stream,
                           (float*)d_out, 2000.0f);
        return;
    }
    const int exp_sizes[12] = {6400000, 1600000, 50000, 4096, 16384, 128,
                               16384, 128, 20480, 128, 256, 2};
    for (int i = 0; i < 12; ++i) {
        if (in_sizes[i] != exp_sizes[i]) {
            hipLaunchKernelGGL(mark_kernel, dim3(1), dim3(128), 0, stream,
                               (float*)d_out, 3000.0f + 100.0f * i);
            return;
        }
    }

    size_t off = 0;
    char* base = (char*)d_ws;
#define WSALLOC(ptr, type, nbytes) \
    type* ptr = (type*)(base + off); off += (((size_t)(nbytes)) + 255) & ~(size_t)255;
    WSALLOC(bufA,  unsigned int, (size_t)NN * FDH * 4)
    WSALLOC(bufB,  unsigned int, (size_t)NN * FDH * 4)
    WSALLOC(dinv,  float, (size_t)NN * 4)
    WSALLOC(degi,  int,   (size_t)NN * 4)
    WSALLOC(tsum,  int,   256 * 4)
    WSALLOC(rowst, int,   (size_t)(NN + 1) * 4)
    WSALLOC(cursor,int,   (size_t)NN * 4)
    WSALLOC(cv,    unsigned int, (size_t)EETOT * 4)
    WSALLOC(gstart,int,   (size_t)(NG + 1) * 4)
    WSALLOC(ebsd,  int2,  (size_t)NCHK * ECHK * 8)
    WSALLOC(bofs,  int,   (size_t)NCHK * 8 * 4)
    WSALLOC(W1t,   unsigned int, (size_t)FD * FDH * 4)
    WSALLOC(W2t,   unsigned int, (size_t)FD * FDH * 4)
    WSALLOC(b1f,   float, FD * 4)
    WSALLOC(b2f,   float, FD * 4)
    WSALLOC(addff, float, (size_t)NG * FA * 4)
    WSALLOC(fc1wf, float, (size_t)(FD + FA) * FD * 4)
    WSALLOC(fc1bf, float, FD * 4)
    WSALLOC(fc2wf, float, FD * 2 * 4)
    WSALLOC(fc2bf, float, 2 * 4)
#undef WSALLOC
    if (ws_size < off) {
        hipLaunchKernelGGL(mark_kernel, dim3(1), dim3(128), 0, stream,
                           (float*)d_out, 1000.0f);
        return;
    }

    const int* ei    = (const int*)d_in[1];
    const int* batch = (const int*)d_in[2];

    hipLaunchKernelGGL(prep, dim3(360), dim3(256), 0, stream,
                       d_in[3], d_in[4], d_in[5], d_in[6], d_in[7],
                       d_in[8], d_in[9], d_in[10], d_in[11],
                       W1t, W2t, addff, b1f, b2f, fc1wf, fc1bf,
                       fc2wf, fc2bf, degi, tsum);

    hipLaunchKernelGGL(bin_kernel, dim3(NCHK), dim3(256), 0, stream,
                       ei, degi, ebsd, bofs);

    hipLaunchKernelGGL(scan_gemm1, dim3(NBLK + GEMMB), dim3(256), 0, stream,
                       degi, batch, tsum, dinv, rowst, cursor, gstart,
                       d_in[0], W1t, (unsigned short*)bufA);

    hipLaunchKernelGGL(fill_kernel, dim3(FILLB), dim3(256), 0, stream,
                       ebsd, bofs, dinv, cursor, cv);

    hipLaunchKernelGGL(aggregate_kernel, dim3(NN / 16), dim3(256), 0, stream,
                       bufA, cv, rowst, b1f, bufB);
    hipLaunchKernelGGL(gemm_mfma, dim3(GEMMB), dim3(256), 0, stream,
                       bufB, W2t, (unsigned short*)bufA);
    hipLaunchKernelGGL(aggregate_kernel, dim3(NN / 16), dim3(256), 0, stream,
                       bufA, cv, rowst, b2f, bufB);

    hipLaunchKernelGGL(poolhead, dim3(NG), dim3(256), 0, stream,
                       bufB, gstart, addff, fc1wf, fc1bf, fc2wf, fc2bf,
                       (const unsigned int*)d_in[0], d_out);
}

// Round 12
// 290.732 us; speedup vs baseline: 1.0207x; 1.0207x over previous
//
#include <hip/hip_runtime.h>

#define NN 50000
#define NE 800000
#define FD 128
#define FDH 64            // FD/2 packed bf16 pairs
#define FA 32
#define NG 128
#define EETOT (NE + NN)
#define NBLK ((NN + 255) / 256)   // 196 scan tiles
#define NPXCD 6250                // nodes per XCD-parity bin
#define ECHK 2048                 // edges per bin chunk
#define NCHK ((NE + ECHK - 1) / ECHK)   // 391 chunks
#define FPB 52                    // fill block-groups per parity
#define FILLB (8 * FPB)           // 416 fill blocks
#define GEMMB ((NN + 63) / 64)    // 782 gemm blocks

typedef __attribute__((ext_vector_type(8))) short short8;
typedef __attribute__((ext_vector_type(4))) float f32x4;

// ---------- bf16 helpers ----------
__device__ __forceinline__ float bfbits(unsigned short u) {
    return __uint_as_float(((unsigned int)u) << 16);
}
__device__ __forceinline__ float bflo(unsigned int p) { return __uint_as_float(p << 16); }
__device__ __forceinline__ float bfhi(unsigned int p) { return __uint_as_float(p & 0xffff0000u); }
__device__ __forceinline__ unsigned short f2bf(float f) {   // RNE
    unsigned int u = __float_as_uint(f);
    unsigned int r = u + 0x7FFFu + ((u >> 16) & 1u);
    return (unsigned short)(r >> 16);
}
__device__ __forceinline__ unsigned int packbf(float a, float b) {
    return (unsigned int)f2bf(a) | ((unsigned int)f2bf(b) << 16);
}

// ---------- inline wave-parallel dtype probes ----------
__device__ __forceinline__ int wave_probe_bf16(const unsigned int* t, int nwords) {
    int lane = threadIdx.x & 63;
    unsigned int wv = (lane < nwords) ? t[lane] : 0u;
    int nzp = (wv != 0u) ? 1 : 0;
    unsigned int e = (wv >> 7) & 0xFFu;
    int hitp = (nzp && e >= 100u && e <= 140u) ? 1 : 0;
    int nz = __popcll(__ballot(nzp));
    int hits = __popcll(__ballot(hitp));
    return (nz < 8) ? 1 : (hits * 4 >= nz * 3);
}
__device__ __forceinline__ int wave_probe_is64(const int* ei) {
    int lane = threadIdx.x & 63;
    int v = (lane < 32) ? ei[2 * lane + 1] : 0;
    return (__ballot(v != 0) == 0ull) ? 1 : 0;
}

// ---------- sentinels ----------
__global__ __launch_bounds__(128) void mark_kernel(float* out, float v) {
    out[threadIdx.x] = v;
}

// ---------- prep: weights + params + zero {degi,tsum} (proven r8/r11) ----------
__global__ __launch_bounds__(256) void prep(
        const void* addf, const void* w1, const void* b1, const void* w2,
        const void* b2, const void* fc1w, const void* fc1b, const void* fc2w,
        const void* fc2b, unsigned int* W1t, unsigned int* W2t,
        float* addff, float* b1f, float* b2f, float* fc1wf, float* fc1bf,
        float* fc2wf, float* fc2bf, int* degi, int* tsum) {
    int b = blockIdx.x;
    if (b < 64) {
        int rel = b * 256 + threadIdx.x;             // [0,16384)
        const void* src = (rel < 8192) ? w1 : w2;
        unsigned int* dst = (rel < 8192) ? W1t : W2t;
        int flag = wave_probe_bf16((const unsigned int*)src, 64);
        int rr = rel & 8191;
        int n = rr >> 6, kk = rr & 63;
        float lo, hi;
        if (flag) {
            const unsigned short* s = (const unsigned short*)src;
            lo = bfbits(s[(2 * kk) * FD + n]);
            hi = bfbits(s[(2 * kk + 1) * FD + n]);
        } else {
            const float* s = (const float*)src;
            lo = s[(2 * kk) * FD + n];
            hi = s[(2 * kk + 1) * FD + n];
        }
        dst[rr] = packbf(lo, hi);
    } else if (b < 163) {
        int i = (b - 64) * 256 + threadIdx.x;        // [0,25344)
        int wb = (b - 64) * 256 + (threadIdx.x & ~63);  // wave base
        const void* src; float* dst; int base; int prnw; int lim;
        if      (wb < 4096)  { src = addf; dst = addff; base = 0;     prnw = 64; lim = 4096;  }
        else if (wb < 4224)  { src = b1;   dst = b1f;   base = 4096;  prnw = 64; lim = 128;   }
        else if (wb < 4352)  { src = b2;   dst = b2f;   base = 4224;  prnw = 64; lim = 128;   }
        else if (wb < 24832) { src = fc1w; dst = fc1wf; base = 4352;  prnw = 64; lim = 20480; }
        else if (wb < 24960) { src = fc1b; dst = fc1bf; base = 24832; prnw = 64; lim = 128;   }
        else if (wb < 25216) { src = fc2w; dst = fc2wf; base = 24960; prnw = 64; lim = 256;   }
        else if (wb < 25280) { src = fc2b; dst = fc2bf; base = 25216; prnw = 1;  lim = 2;     }
        else return;
        int flag = wave_probe_bf16((const unsigned int*)src, prnw);
        int rel = i - base;
        if (rel < lim) {
            if (flag) dst[rel] = bfbits(((const unsigned short*)src)[rel]);
            else      dst[rel] = ((const float*)src)[rel];
        }
    } else {
        int i = (b - 163) * 256 + threadIdx.x;
        if      (i < NN)       degi[i] = 0;
        else if (i < NN + 256) tsum[i - NN] = 0;
    }
}

// ---------- merged: chunk-binning (blocks < NCHK) + GEMM1 (blocks >= NCHK) -------
// bin is pure streaming (ei in, ebsd out, LDS ranks) — no residency-sensitive
// state, no spin-waits; gemm1 needs only prep's W1t + input x. Both halves always
// complete -> safe co-schedule.
__global__ __launch_bounds__(256) void bin_gemm1(const int* ei, int* deg,
        int2* ebsd, int* bofs,
        const void* __restrict__ Av, const unsigned int* __restrict__ Wt,
        unsigned short* __restrict__ C) {
    if ((int)blockIdx.x < NCHK) {
        __shared__ int cnt[8];
        __shared__ int sbase[8];
        int is64 = wave_probe_is64(ei);
        int chunk = blockIdx.x;
        int e0 = chunk * ECHK;
        int nedge = NE - e0; if (nedge > ECHK) nedge = ECHK;
        if (threadIdx.x < 8) cnt[threadIdx.x] = 0;
        __syncthreads();
        int sA[8], dA[8], rk[8], pr[8];
        #pragma unroll
        for (int k = 0; k < 8; ++k) {
            int j = k * 256 + threadIdx.x;
            pr[k] = -1;
            if (j < nedge) {
                int e = e0 + j;
                int s = is64 ? ei[2 * e] : ei[e];
                int d = is64 ? ei[2 * (NE + e)] : ei[NE + e];
                atomicAdd(&deg[d], 1);          // spread over 50K addrs: cheap
                int p = d / NPXCD;
                sA[k] = s; dA[k] = d; pr[k] = p;
                rk[k] = atomicAdd(&cnt[p], 1);  // LDS atomic: on-CU, fast
            }
        }
        __syncthreads();
        if (threadIdx.x == 0) {
            int acc = 0;
            #pragma unroll
            for (int p = 0; p < 8; ++p) {
                sbase[p] = acc;
                bofs[chunk * 8 + p] = acc;
                acc += cnt[p];
            }
        }
        __syncthreads();
        #pragma unroll
        for (int k = 0; k < 8; ++k) {
            if (pr[k] >= 0) {
                int idx = chunk * ECHK + sbase[pr[k]] + rk[k];
                ebsd[idx] = make_int2(sA[k], dA[k]);
            }
        }
        return;
    }
    // ---- gemm1: C[NN][128] = toBF16(A) @ W1t, A possibly fp32 ----
    int bid = blockIdx.x - NCHK;
    int wave = threadIdx.x >> 6;
    int lane = threadIdx.x & 63;
    int quad = lane >> 4;
    int l16  = lane & 15;
    int mbase = bid * 64 + wave * 16;
    int ra = mbase + l16;
    if (ra >= NN) ra = NN - 1;
    bool f32in = !wave_probe_bf16((const unsigned int*)Av, 64);
    short8 af[4];
    if (!f32in) {
        const uint4* Arow = (const uint4*)((const unsigned int*)Av + (size_t)ra * FDH);
        #pragma unroll
        for (int kk = 0; kk < 4; ++kk) {
            uint4 v = Arow[kk * 4 + quad];
            af[kk] = *(short8*)&v;
        }
    } else {
        const float* Arow = (const float*)Av + (size_t)ra * FD;
        #pragma unroll
        for (int kk = 0; kk < 4; ++kk) {
            const float4* p = (const float4*)(Arow + (kk * 4 + quad) * 8);
            float4 u = p[0], v = p[1];
            uint4 q;
            q.x = packbf(u.x, u.y); q.y = packbf(u.z, u.w);
            q.z = packbf(v.x, v.y); q.w = packbf(v.z, v.w);
            af[kk] = *(short8*)&q;
        }
    }
    #pragma unroll
    for (int nt = 0; nt < 8; ++nt) {
        int n = nt * 16 + l16;
        const uint4* Wrow = (const uint4*)(Wt + (size_t)n * FDH);
        f32x4 acc = {0.f, 0.f, 0.f, 0.f};
        #pragma unroll
        for (int kk = 0; kk < 4; ++kk) {
            uint4 wv = Wrow[kk * 4 + quad];
            short8 bf = *(short8*)&wv;
            acc = __builtin_amdgcn_mfma_f32_16x16x32_bf16(af[kk], bf, acc, 0, 0, 0);
        }
        int row0 = mbase + quad * 4;
        #pragma unroll
        for (int reg = 0; reg < 4; ++reg) {
            int r = row0 + reg;
            if (r < NN) C[(size_t)r * FD + nt * 16 + l16] = f2bf(acc[reg]);
        }
    }
}

// ---------- fused scan: standalone (no co-scheduled bulk work -> spin is cheap) --
__global__ __launch_bounds__(256) void scan_fused(const int* degi, const int* batch,
        int* tsum, float* dinv, int* rowstart, int* cursor, int* gstart) {
    __shared__ int sh[256];
    int b = blockIdx.x, t = threadIdx.x;
    int i = b * 256 + t;
    int d = (i < NN) ? degi[i] : 0;
    if (i < NN) dinv[i] = rsqrtf((float)(d + 1));
    int v = (i < NN) ? d + 1 : 0;
    sh[t] = v;
    __syncthreads();
    for (int off = 1; off < 256; off <<= 1) {
        int a = (t >= off) ? sh[t - off] : 0;
        __syncthreads();
        sh[t] += a;
        __syncthreads();
    }
    int incl = sh[t];
    int total = sh[255];
    if (t == 0) atomicExch(&tsum[b], total);   // publish first; total >= 80 > 0
    int pt = 0;
    for (int j = t; j < b; j += 256) {
        int s;
        do { s = atomicAdd(&tsum[j], 0); } while (s == 0);
        pt += s;
    }
    __syncthreads();
    sh[t] = pt;
    __syncthreads();
    for (int off = 128; off >= 1; off >>= 1) {
        if (t < off) sh[t] += sh[t + off];
        __syncthreads();
    }
    int boff = sh[0];
    if (i < NN) {
        int r = boff + incl - v;
        rowstart[i] = r;
        cursor[i]   = r;
    }
    if (i == 0) rowstart[NN] = EETOT;
    if (i < NN) {
        int is64 = (batch[NN - 1] == 0) ? 1 : 0;
        int bc = is64 ? batch[2 * i] : batch[i];
        if (i == 0) {
            for (int g = 0; g <= bc; ++g) gstart[g] = 0;
        } else {
            int bp = is64 ? batch[2 * (i - 1)] : batch[i - 1];
            for (int g = bp + 1; g <= bc; ++g) gstart[g] = i;
        }
        if (i == NN - 1) {
            for (int g = bc + 1; g <= NG; ++g) gstart[g] = NN;
        }
    }
}

// ---------- binned CSR fill (standalone: cv lines stay L2-resident) ----------
__global__ __launch_bounds__(256) void fill_kernel(const int2* ebsd, const int* bofs,
        const float* dinv, int* cursor, unsigned int* cv) {
    int par = blockIdx.x & 7;        // matches XCD round-robin
    int g   = blockIdx.x >> 3;       // group within parity [0,FPB)
    for (int chunk = g; chunk < NCHK; chunk += FPB) {
        int b0 = bofs[chunk * 8 + par];
        int nedge = NE - chunk * ECHK; if (nedge > ECHK) nedge = ECHK;
        int b1 = (par < 7) ? bofs[chunk * 8 + par + 1] : nedge;
        for (int j = b0 + (int)threadIdx.x; j < b1; j += 256) {
            int2 sd = ebsd[chunk * ECHK + j];
            int pos = atomicAdd(&cursor[sd.y], 1);
            cv[pos] = (unsigned int)sd.x
                    | ((unsigned int)f2bf(dinv[sd.x] * dinv[sd.y]) << 16);
        }
    }
    // self-loops for this parity's node range
    for (int n = par * NPXCD + g * 256 + threadIdx.x; n < (par + 1) * NPXCD;
         n += FPB * 256) {
        int pos = atomicAdd(&cursor[n], 1);
        float di = dinv[n];
        cv[pos] = (unsigned int)n | ((unsigned int)f2bf(di * di) << 16);
    }
}

// ---------- standalone MFMA GEMM (layer 2, bf16 input) ----------
__global__ __launch_bounds__(256) void gemm_mfma(const unsigned int* __restrict__ Av,
        const unsigned int* __restrict__ Wt, unsigned short* __restrict__ C) {
    int wave = threadIdx.x >> 6;
    int lane = threadIdx.x & 63;
    int quad = lane >> 4;
    int l16  = lane & 15;
    int mbase = blockIdx.x * 64 + wave * 16;
    int ra = mbase + l16;
    if (ra >= NN) ra = NN - 1;
    short8 af[4];
    const uint4* Arow = (const uint4*)(Av + (size_t)ra * FDH);
    #pragma unroll
    for (int kk = 0; kk < 4; ++kk) {
        uint4 v = Arow[kk * 4 + quad];
        af[kk] = *(short8*)&v;
    }
    #pragma unroll
    for (int nt = 0; nt < 8; ++nt) {
        int n = nt * 16 + l16;
        const uint4* Wrow = (const uint4*)(Wt + (size_t)n * FDH);
        f32x4 acc = {0.f, 0.f, 0.f, 0.f};
        #pragma unroll
        for (int kk = 0; kk < 4; ++kk) {
            uint4 wv = Wrow[kk * 4 + quad];
            short8 bf = *(short8*)&wv;
            acc = __builtin_amdgcn_mfma_f32_16x16x32_bf16(af[kk], bf, acc, 0, 0, 0);
        }
        int row0 = mbase + quad * 4;
        #pragma unroll
        for (int reg = 0; reg < 4; ++reg) {
            int r = row0 + reg;
            if (r < NN) C[(size_t)r * FD + nt * 16 + l16] = f2bf(acc[reg]);
        }
    }
}

// ---------- CSR aggregation: uint4 gathers, 4 rows/wave, 16 rows/block ----------
__global__ __launch_bounds__(256) void aggregate_kernel(const unsigned int* Hb,
        const unsigned int* cv, const int* rowstart, const float* bias,
        unsigned int* outb) {
    int lane = threadIdx.x & 63;
    int r4   = lane >> 4;            // row within wave 0..3
    int c4   = lane & 15;            // uint4 index within 64-word row
    int wv   = threadIdx.x >> 6;
    int n = blockIdx.x * 16 + wv * 4 + r4;   // NN % 16 == 0
    const uint4* H4 = (const uint4*)Hb;
    int jb = rowstart[n], je = rowstart[n + 1];
    float a0 = 0.f, a1 = 0.f, a2 = 0.f, a3 = 0.f;
    float a4 = 0.f, a5 = 0.f, a6 = 0.f, a7 = 0.f;
    int j = jb;
    for (; j + 7 < je; j += 8) {
        unsigned int rr[8]; uint4 hh[8];
        #pragma unroll
        for (int k = 0; k < 8; ++k) rr[k] = cv[j + k];
        #pragma unroll
        for (int k = 0; k < 8; ++k) hh[k] = H4[(size_t)(rr[k] & 0xFFFFu) * 16 + c4];
        #pragma unroll
        for (int k = 0; k < 8; ++k) {
            float v = bfbits((unsigned short)(rr[k] >> 16));
            a0 += v * bflo(hh[k].x); a1 += v * bfhi(hh[k].x);
            a2 += v * bflo(hh[k].y); a3 += v * bfhi(hh[k].y);
            a4 += v * bflo(hh[k].z); a5 += v * bfhi(hh[k].z);
            a6 += v * bflo(hh[k].w); a7 += v * bfhi(hh[k].w);
        }
    }
    for (; j + 3 < je; j += 4) {
        unsigned int rr[4]; uint4 hh[4];
        #pragma unroll
        for (int k = 0; k < 4; ++k) rr[k] = cv[j + k];
        #pragma unroll
        for (int k = 0; k < 4; ++k) hh[k] = H4[(size_t)(rr[k] & 0xFFFFu) * 16 + c4];
        #pragma unroll
        for (int k = 0; k < 4; ++k) {
            float v = bfbits((unsigned short)(rr[k] >> 16));
            a0 += v * bflo(hh[k].x); a1 += v * bfhi(hh[k].x);
            a2 += v * bflo(hh[k].y); a3 += v * bfhi(hh[k].y);
            a4 += v * bflo(hh[k].z); a5 += v * bfhi(hh[k].z);
            a6 += v * bflo(hh[k].w); a7 += v * bfhi(hh[k].w);
        }
    }
    for (; j < je; ++j) {
        unsigned int r = cv[j];
        uint4 h = H4[(size_t)(r & 0xFFFFu) * 16 + c4];
        float v = bfbits((unsigned short)(r >> 16));
        a0 += v * bflo(h.x); a1 += v * bfhi(h.x);
        a2 += v * bflo(h.y); a3 += v * bfhi(h.y);
        a4 += v * bflo(h.z); a5 += v * bfhi(h.z);
        a6 += v * bflo(h.w); a7 += v * bfhi(h.w);
    }
    a0 = fmaxf(a0 + bias[8 * c4 + 0], 0.f);
    a1 = fmaxf(a1 + bias[8 * c4 + 1], 0.f);
    a2 = fmaxf(a2 + bias[8 * c4 + 2], 0.f);
    a3 = fmaxf(a3 + bias[8 * c4 + 3], 0.f);
    a4 = fmaxf(a4 + bias[8 * c4 + 4], 0.f);
    a5 = fmaxf(a5 + bias[8 * c4 + 5], 0.f);
    a6 = fmaxf(a6 + bias[8 * c4 + 6], 0.f);
    a7 = fmaxf(a7 + bias[8 * c4 + 7], 0.f);
    uint4 out;
    out.x = packbf(a0, a1);
    out.y = packbf(a2, a3);
    out.z = packbf(a4, a5);
    out.w = packbf(a6, a7);
    ((uint4*)outb)[(size_t)n * 16 + c4] = out;
}

// ---------- fused mean-pool + MLP head ----------
__global__ __launch_bounds__(256) void poolhead(const unsigned int* Hb,
        const int* gstart, const float* addf, const float* fc1w, const float* fc1b,
        const float* fc2w, const float* fc2b, const unsigned int* x, void* outp) {
    int g = blockIdx.x;
    int t = threadIdx.x;
    int q = t >> 6, w = t & 63;
    int obf = wave_probe_bf16(x, 64);
    int s = gstart[g], e = gstart[g + 1];
    float a0 = 0.f, a1 = 0.f;
    #pragma unroll 4
    for (int n = s + q; n < e; n += 4) {
        unsigned int h = Hb[(size_t)n * FDH + w];
        a0 += bflo(h);
        a1 += bfhi(h);
    }
    __shared__ float pp[4][FD];
    __shared__ float z[FD + FA];
    __shared__ float h[FD];
    pp[q][2 * w]     = a0;
    pp[q][2 * w + 1] = a1;
    __syncthreads();
    if (t < FD) {
        float cnt = (float)(e - s);
        if (cnt < 1.0f) cnt = 1.0f;
        z[t] = (pp[0][t] + pp[1][t] + pp[2][t] + pp[3][t]) / cnt;
    }
    if (t >= FD && t < FD + FA) z[t] = addf[g * FA + (t - FD)];
    __syncthreads();
    if (t < FD) {
        float acc = fc1b[t];
        #pragma unroll 4
        for (int k = 0; k < FD + FA; ++k)
            acc += z[k] * fc1w[k * FD + t];
        h[t] = fmaxf(acc, 0.f);
    }
    __syncthreads();
    if (t < 2) {
        float o = fc2b[t];
        for (int j = 0; j < FD; ++j) o += h[j] * fc2w[j * 2 + t];
        if (obf) ((unsigned short*)outp)[g * 2 + t] = f2bf(o);
        else     ((float*)outp)[g * 2 + t] = o;
    }
}

extern "C" void kernel_launch(void* const* d_in, const int* in_sizes, int n_in,
                              void* d_out, int out_size, void* d_ws, size_t ws_size,
                              hipStream_t stream) {
    (void)out_size;

    if (n_in != 12) {
        hipLaunchKernelGGL(mark_kernel, dim3(1), dim3(128), 0, stream,
                           (float*)d_out, 2000.0f);
        return;
    }
    const int exp_sizes[12] = {6400000, 1600000, 50000, 4096, 16384, 128,
                               16384, 128, 20480, 128, 256, 2};
    for (int i = 0; i < 12; ++i) {
        if (in_sizes[i] != exp_sizes[i]) {
            hipLaunchKernelGGL(mark_kernel, dim3(1), dim3(128), 0, stream,
                               (float*)d_out, 3000.0f + 100.0f * i);
            return;
        }
    }

    size_t off = 0;
    char* base = (char*)d_ws;
#define WSALLOC(ptr, type, nbytes) \
    type* ptr = (type*)(base + off); off += (((size_t)(nbytes)) + 255) & ~(size_t)255;
    WSALLOC(bufA,  unsigned int, (size_t)NN * FDH * 4)
    WSALLOC(bufB,  unsigned int, (size_t)NN * FDH * 4)
    WSALLOC(dinv,  float, (size_t)NN * 4)
    WSALLOC(degi,  int,   (size_t)NN * 4)
    WSALLOC(tsum,  int,   256 * 4)
    WSALLOC(rowst, int,   (size_t)(NN + 1) * 4)
    WSALLOC(cursor,int,   (size_t)NN * 4)
    WSALLOC(cv,    unsigned int, (size_t)EETOT * 4)
    WSALLOC(gstart,int,   (size_t)(NG + 1) * 4)
    WSALLOC(ebsd,  int2,  (size_t)NCHK * ECHK * 8)
    WSALLOC(bofs,  int,   (size_t)NCHK * 8 * 4)
    WSALLOC(W1t,   unsigned int, (size_t)FD * FDH * 4)
    WSALLOC(W2t,   unsigned int, (size_t)FD * FDH * 4)
    WSALLOC(b1f,   float, FD * 4)
    WSALLOC(b2f,   float, FD * 4)
    WSALLOC(addff, float, (size_t)NG * FA * 4)
    WSALLOC(fc1wf, float, (size_t)(FD + FA) * FD * 4)
    WSALLOC(fc1bf, float, FD * 4)
    WSALLOC(fc2wf, float, FD * 2 * 4)
    WSALLOC(fc2bf, float, 2 * 4)
#undef WSALLOC
    if (ws_size < off) {
        hipLaunchKernelGGL(mark_kernel, dim3(1), dim3(128), 0, stream,
                           (float*)d_out, 1000.0f);
        return;
    }

    const int* ei    = (const int*)d_in[1];
    const int* batch = (const int*)d_in[2];

    hipLaunchKernelGGL(prep, dim3(360), dim3(256), 0, stream,
                       d_in[3], d_in[4], d_in[5], d_in[6], d_in[7],
                       d_in[8], d_in[9], d_in[10], d_in[11],
                       W1t, W2t, addff, b1f, b2f, fc1wf, fc1bf,
                       fc2wf, fc2bf, degi, tsum);

    hipLaunchKernelGGL(bin_gemm1, dim3(NCHK + GEMMB), dim3(256), 0, stream,
                       ei, degi, ebsd, bofs,
                       d_in[0], W1t, (unsigned short*)bufA);

    hipLaunchKernelGGL(scan_fused, dim3(NBLK), dim3(256), 0, stream,
                       degi, batch, tsum, dinv, rowst, cursor, gstart);

    hipLaunchKernelGGL(fill_kernel, dim3(FILLB), dim3(256), 0, stream,
                       ebsd, bofs, dinv, cursor, cv);

    hipLaunchKernelGGL(aggregate_kernel, dim3(NN / 16), dim3(256), 0, stream,
                       bufA, cv, rowst, b1f, bufB);
    hipLaunchKernelGGL(gemm_mfma, dim3(GEMMB), dim3(256), 0, stream,
                       bufB, W2t, (unsigned short*)bufA);
    hipLaunchKernelGGL(aggregate_kernel, dim3(NN / 16), dim3(256), 0, stream,
                       bufA, cv, rowst, b2f, bufB);

    hipLaunchKernelGGL(poolhead, dim3(NG), dim3(256), 0, stream,
                       bufB, gstart, addff, fc1wf, fc1bf, fc2wf, fc2bf,
                       (const unsigned int*)d_in[0], d_out);
}

// Round 13
// 278.920 us; speedup vs baseline: 1.0639x; 1.0424x over previous
//
#include <hip/hip_runtime.h>

#define NN 50000
#define NE 800000
#define FD 128
#define FDH 64            // FD/2 packed bf16 pairs
#define FA 32
#define NG 128
#define EETOT (NE + NN)
#define NBLK ((NN + 255) / 256)   // 196 scan tiles
#define NPXCD 6250                // nodes per XCD-parity bin
#define ECHK 2048                 // edges per bin chunk
#define NCHK ((NE + ECHK - 1) / ECHK)   // 391 chunks
#define FPB 52                    // fill block-groups per parity
#define FILLB (8 * FPB)           // 416 fill blocks
#define GEMMB ((NN + 63) / 64)    // 782 gemm blocks

typedef __attribute__((ext_vector_type(8))) short short8;
typedef __attribute__((ext_vector_type(4))) float f32x4;

// ---------- bf16 helpers ----------
__device__ __forceinline__ float bfbits(unsigned short u) {
    return __uint_as_float(((unsigned int)u) << 16);
}
__device__ __forceinline__ float bflo(unsigned int p) { return __uint_as_float(p << 16); }
__device__ __forceinline__ float bfhi(unsigned int p) { return __uint_as_float(p & 0xffff0000u); }
__device__ __forceinline__ unsigned short f2bf(float f) {   // RNE
    unsigned int u = __float_as_uint(f);
    unsigned int r = u + 0x7FFFu + ((u >> 16) & 1u);
    return (unsigned short)(r >> 16);
}
__device__ __forceinline__ unsigned int packbf(float a, float b) {
    return (unsigned int)f2bf(a) | ((unsigned int)f2bf(b) << 16);
}

// ---------- inline wave-parallel dtype probes ----------
__device__ __forceinline__ int wave_probe_bf16(const unsigned int* t, int nwords) {
    int lane = threadIdx.x & 63;
    unsigned int wv = (lane < nwords) ? t[lane] : 0u;
    int nzp = (wv != 0u) ? 1 : 0;
    unsigned int e = (wv >> 7) & 0xFFu;
    int hitp = (nzp && e >= 100u && e <= 140u) ? 1 : 0;
    int nz = __popcll(__ballot(nzp));
    int hits = __popcll(__ballot(hitp));
    return (nz < 8) ? 1 : (hits * 4 >= nz * 3);
}
__device__ __forceinline__ int wave_probe_is64(const int* ei) {
    int lane = threadIdx.x & 63;
    int v = (lane < 32) ? ei[2 * lane + 1] : 0;
    return (__ballot(v != 0) == 0ull) ? 1 : 0;
}

// ---------- sentinels ----------
__global__ __launch_bounds__(128) void mark_kernel(float* out, float v) {
    out[threadIdx.x] = v;
}

// ---------- prep: weights + params + zero {degi,tsum} (proven r8/r11/r12) --------
__global__ __launch_bounds__(256) void prep(
        const void* addf, const void* w1, const void* b1, const void* w2,
        const void* b2, const void* fc1w, const void* fc1b, const void* fc2w,
        const void* fc2b, unsigned int* W1t, unsigned int* W2t,
        float* addff, float* b1f, float* b2f, float* fc1wf, float* fc1bf,
        float* fc2wf, float* fc2bf, int* degi, int* tsum) {
    int b = blockIdx.x;
    if (b < 64) {
        int rel = b * 256 + threadIdx.x;             // [0,16384)
        const void* src = (rel < 8192) ? w1 : w2;
        unsigned int* dst = (rel < 8192) ? W1t : W2t;
        int flag = wave_probe_bf16((const unsigned int*)src, 64);
        int rr = rel & 8191;
        int n = rr >> 6, kk = rr & 63;
        float lo, hi;
        if (flag) {
            const unsigned short* s = (const unsigned short*)src;
            lo = bfbits(s[(2 * kk) * FD + n]);
            hi = bfbits(s[(2 * kk + 1) * FD + n]);
        } else {
            const float* s = (const float*)src;
            lo = s[(2 * kk) * FD + n];
            hi = s[(2 * kk + 1) * FD + n];
        }
        dst[rr] = packbf(lo, hi);
    } else if (b < 163) {
        int i = (b - 64) * 256 + threadIdx.x;        // [0,25344)
        int wb = (b - 64) * 256 + (threadIdx.x & ~63);  // wave base
        const void* src; float* dst; int base; int prnw; int lim;
        if      (wb < 4096)  { src = addf; dst = addff; base = 0;     prnw = 64; lim = 4096;  }
        else if (wb < 4224)  { src = b1;   dst = b1f;   base = 4096;  prnw = 64; lim = 128;   }
        else if (wb < 4352)  { src = b2;   dst = b2f;   base = 4224;  prnw = 64; lim = 128;   }
        else if (wb < 24832) { src = fc1w; dst = fc1wf; base = 4352;  prnw = 64; lim = 20480; }
        else if (wb < 24960) { src = fc1b; dst = fc1bf; base = 24832; prnw = 64; lim = 128;   }
        else if (wb < 25216) { src = fc2w; dst = fc2wf; base = 24960; prnw = 64; lim = 256;   }
        else if (wb < 25280) { src = fc2b; dst = fc2bf; base = 25216; prnw = 1;  lim = 2;     }
        else return;
        int flag = wave_probe_bf16((const unsigned int*)src, prnw);
        int rel = i - base;
        if (rel < lim) {
            if (flag) dst[rel] = bfbits(((const unsigned short*)src)[rel]);
            else      dst[rel] = ((const float*)src)[rel];
        }
    } else {
        int i = (b - 163) * 256 + threadIdx.x;
        if      (i < NN)       degi[i] = 0;
        else if (i < NN + 256) tsum[i - NN] = 0;
    }
}

// ---------- merged: chunk-binning (blocks < NCHK) + GEMM1 (blocks >= NCHK) -------
__global__ __launch_bounds__(256) void bin_gemm1(const int* ei, int* deg,
        int2* ebsd, int* bofs,
        const void* __restrict__ Av, const unsigned int* __restrict__ Wt,
        unsigned short* __restrict__ C) {
    if ((int)blockIdx.x < NCHK) {
        __shared__ int cnt[8];
        __shared__ int sbase[8];
        int is64 = wave_probe_is64(ei);
        int chunk = blockIdx.x;
        int e0 = chunk * ECHK;
        int nedge = NE - e0; if (nedge > ECHK) nedge = ECHK;
        if (threadIdx.x < 8) cnt[threadIdx.x] = 0;
        __syncthreads();
        int sA[8], dA[8], rk[8], pr[8];
        #pragma unroll
        for (int k = 0; k < 8; ++k) {
            int j = k * 256 + threadIdx.x;
            pr[k] = -1;
            if (j < nedge) {
                int e = e0 + j;
                int s = is64 ? ei[2 * e] : ei[e];
                int d = is64 ? ei[2 * (NE + e)] : ei[NE + e];
                atomicAdd(&deg[d], 1);          // spread over 50K addrs: cheap
                int p = d / NPXCD;
                sA[k] = s; dA[k] = d; pr[k] = p;
                rk[k] = atomicAdd(&cnt[p], 1);  // LDS atomic: on-CU, fast
            }
        }
        __syncthreads();
        if (threadIdx.x == 0) {
            int acc = 0;
            #pragma unroll
            for (int p = 0; p < 8; ++p) {
                sbase[p] = acc;
                bofs[chunk * 8 + p] = acc;
                acc += cnt[p];
            }
        }
        __syncthreads();
        #pragma unroll
        for (int k = 0; k < 8; ++k) {
            if (pr[k] >= 0) {
                int idx = chunk * ECHK + sbase[pr[k]] + rk[k];
                ebsd[idx] = make_int2(sA[k], dA[k]);
            }
        }
        return;
    }
    // ---- gemm1: C[NN][128] = toBF16(A) @ W1t, A possibly fp32 ----
    int bid = blockIdx.x - NCHK;
    int wave = threadIdx.x >> 6;
    int lane = threadIdx.x & 63;
    int quad = lane >> 4;
    int l16  = lane & 15;
    int mbase = bid * 64 + wave * 16;
    int ra = mbase + l16;
    if (ra >= NN) ra = NN - 1;
    bool f32in = !wave_probe_bf16((const unsigned int*)Av, 64);
    short8 af[4];
    if (!f32in) {
        const uint4* Arow = (const uint4*)((const unsigned int*)Av + (size_t)ra * FDH);
        #pragma unroll
        for (int kk = 0; kk < 4; ++kk) {
            uint4 v = Arow[kk * 4 + quad];
            af[kk] = *(short8*)&v;
        }
    } else {
        const float* Arow = (const float*)Av + (size_t)ra * FD;
        #pragma unroll
        for (int kk = 0; kk < 4; ++kk) {
            const float4* p = (const float4*)(Arow + (kk * 4 + quad) * 8);
            float4 u = p[0], v = p[1];
            uint4 q;
            q.x = packbf(u.x, u.y); q.y = packbf(u.z, u.w);
            q.z = packbf(v.x, v.y); q.w = packbf(v.z, v.w);
            af[kk] = *(short8*)&q;
        }
    }
    #pragma unroll
    for (int nt = 0; nt < 8; ++nt) {
        int n = nt * 16 + l16;
        const uint4* Wrow = (const uint4*)(Wt + (size_t)n * FDH);
        f32x4 acc = {0.f, 0.f, 0.f, 0.f};
        #pragma unroll
        for (int kk = 0; kk < 4; ++kk) {
            uint4 wv = Wrow[kk * 4 + quad];
            short8 bf = *(short8*)&wv;
            acc = __builtin_amdgcn_mfma_f32_16x16x32_bf16(af[kk], bf, acc, 0, 0, 0);
        }
        int row0 = mbase + quad * 4;
        #pragma unroll
        for (int reg = 0; reg < 4; ++reg) {
            int r = row0 + reg;
            if (r < NN) C[(size_t)r * FD + nt * 16 + l16] = f2bf(acc[reg]);
        }
    }
}

// ---------- fused scan: standalone ----------
__global__ __launch_bounds__(256) void scan_fused(const int* degi, const int* batch,
        int* tsum, float* dinv, int* rowstart, int* cursor, int* gstart) {
    __shared__ int sh[256];
    int b = blockIdx.x, t = threadIdx.x;
    int i = b * 256 + t;
    int d = (i < NN) ? degi[i] : 0;
    if (i < NN) dinv[i] = rsqrtf((float)(d + 1));
    int v = (i < NN) ? d + 1 : 0;
    sh[t] = v;
    __syncthreads();
    for (int off = 1; off < 256; off <<= 1) {
        int a = (t >= off) ? sh[t - off] : 0;
        __syncthreads();
        sh[t] += a;
        __syncthreads();
    }
    int incl = sh[t];
    int total = sh[255];
    if (t == 0) atomicExch(&tsum[b], total);   // publish first; total >= 80 > 0
    int pt = 0;
    for (int j = t; j < b; j += 256) {
        int s;
        do { s = atomicAdd(&tsum[j], 0); } while (s == 0);
        pt += s;
    }
    __syncthreads();
    sh[t] = pt;
    __syncthreads();
    for (int off = 128; off >= 1; off >>= 1) {
        if (t < off) sh[t] += sh[t + off];
        __syncthreads();
    }
    int boff = sh[0];
    if (i < NN) {
        int r = boff + incl - v;
        rowstart[i] = r;
        cursor[i]   = r;
    }
    if (i == 0) rowstart[NN] = EETOT;
    if (i < NN) {
        int is64 = (batch[NN - 1] == 0) ? 1 : 0;
        int bc = is64 ? batch[2 * i] : batch[i];
        if (i == 0) {
            for (int g = 0; g <= bc; ++g) gstart[g] = 0;
        } else {
            int bp = is64 ? batch[2 * (i - 1)] : batch[i - 1];
            for (int g = bp + 1; g <= bc; ++g) gstart[g] = i;
        }
        if (i == NN - 1) {
            for (int g = bc + 1; g <= NG; ++g) gstart[g] = NN;
        }
    }
}

// ---------- binned CSR fill (standalone: cv lines stay L2-resident) ----------
__global__ __launch_bounds__(256) void fill_kernel(const int2* ebsd, const int* bofs,
        const float* dinv, int* cursor, unsigned int* cv) {
    int par = blockIdx.x & 7;        // matches XCD round-robin
    int g   = blockIdx.x >> 3;       // group within parity [0,FPB)
    for (int chunk = g; chunk < NCHK; chunk += FPB) {
        int b0 = bofs[chunk * 8 + par];
        int nedge = NE - chunk * ECHK; if (nedge > ECHK) nedge = ECHK;
        int b1 = (par < 7) ? bofs[chunk * 8 + par + 1] : nedge;
        for (int j = b0 + (int)threadIdx.x; j < b1; j += 256) {
            int2 sd = ebsd[chunk * ECHK + j];
            int pos = atomicAdd(&cursor[sd.y], 1);
            cv[pos] = (unsigned int)sd.x
                    | ((unsigned int)f2bf(dinv[sd.x] * dinv[sd.y]) << 16);
        }
    }
    // self-loops for this parity's node range
    for (int n = par * NPXCD + g * 256 + threadIdx.x; n < (par + 1) * NPXCD;
         n += FPB * 256) {
        int pos = atomicAdd(&cursor[n], 1);
        float di = dinv[n];
        cv[pos] = (unsigned int)n | ((unsigned int)f2bf(di * di) << 16);
    }
}

// ---------- fused: agg layer1 (Phase A) + GEMM2 (Phase B), block = 16 nodes ------
// Phase A is bit-identical to aggregate_kernel but lands the relu'd H1agg tile in
// LDS; Phase B computes C[16][128] = tile @ W2t via MFMA (same fragment mapping
// and K-order as gemm_mfma -> bit-identical). Saves the gemm2 dispatch and the
// 25.6MB bufB round trip.
__global__ __launch_bounds__(256) void agg_gemm2(const unsigned int* Hb,
        const unsigned int* cv, const int* rowstart, const float* bias,
        const unsigned int* __restrict__ Wt, unsigned short* __restrict__ C) {
    __shared__ unsigned int hA[16][68];   // 16 rows x 64 uints, +4 pad (2-way banks)
    int lane = threadIdx.x & 63;
    int r4   = lane >> 4;
    int c4   = lane & 15;
    int wv   = threadIdx.x >> 6;
    int nb = blockIdx.x * 16;            // NN % 16 == 0
    int n = nb + wv * 4 + r4;
    const uint4* H4 = (const uint4*)Hb;
    int jb = rowstart[n], je = rowstart[n + 1];
    float a0 = 0.f, a1 = 0.f, a2 = 0.f, a3 = 0.f;
    float a4 = 0.f, a5 = 0.f, a6 = 0.f, a7 = 0.f;
    int j = jb;
    for (; j + 7 < je; j += 8) {
        unsigned int rr[8]; uint4 hh[8];
        #pragma unroll
        for (int k = 0; k < 8; ++k) rr[k] = cv[j + k];
        #pragma unroll
        for (int k = 0; k < 8; ++k) hh[k] = H4[(size_t)(rr[k] & 0xFFFFu) * 16 + c4];
        #pragma unroll
        for (int k = 0; k < 8; ++k) {
            float v = bfbits((unsigned short)(rr[k] >> 16));
            a0 += v * bflo(hh[k].x); a1 += v * bfhi(hh[k].x);
            a2 += v * bflo(hh[k].y); a3 += v * bfhi(hh[k].y);
            a4 += v * bflo(hh[k].z); a5 += v * bfhi(hh[k].z);
            a6 += v * bflo(hh[k].w); a7 += v * bfhi(hh[k].w);
        }
    }
    for (; j + 3 < je; j += 4) {
        unsigned int rr[4]; uint4 hh[4];
        #pragma unroll
        for (int k = 0; k < 4; ++k) rr[k] = cv[j + k];
        #pragma unroll
        for (int k = 0; k < 4; ++k) hh[k] = H4[(size_t)(rr[k] & 0xFFFFu) * 16 + c4];
        #pragma unroll
        for (int k = 0; k < 4; ++k) {
            float v = bfbits((unsigned short)(rr[k] >> 16));
            a0 += v * bflo(hh[k].x); a1 += v * bfhi(hh[k].x);
            a2 += v * bflo(hh[k].y); a3 += v * bfhi(hh[k].y);
            a4 += v * bflo(hh[k].z); a5 += v * bfhi(hh[k].z);
            a6 += v * bflo(hh[k].w); a7 += v * bfhi(hh[k].w);
        }
    }
    for (; j < je; ++j) {
        unsigned int r = cv[j];
        uint4 h = H4[(size_t)(r & 0xFFFFu) * 16 + c4];
        float v = bfbits((unsigned short)(r >> 16));
        a0 += v * bflo(h.x); a1 += v * bfhi(h.x);
        a2 += v * bflo(h.y); a3 += v * bfhi(h.y);
        a4 += v * bflo(h.z); a5 += v * bfhi(h.z);
        a6 += v * bflo(h.w); a7 += v * bfhi(h.w);
    }
    a0 = fmaxf(a0 + bias[8 * c4 + 0], 0.f);
    a1 = fmaxf(a1 + bias[8 * c4 + 1], 0.f);
    a2 = fmaxf(a2 + bias[8 * c4 + 2], 0.f);
    a3 = fmaxf(a3 + bias[8 * c4 + 3], 0.f);
    a4 = fmaxf(a4 + bias[8 * c4 + 4], 0.f);
    a5 = fmaxf(a5 + bias[8 * c4 + 5], 0.f);
    a6 = fmaxf(a6 + bias[8 * c4 + 6], 0.f);
    a7 = fmaxf(a7 + bias[8 * c4 + 7], 0.f);
    int lrow = wv * 4 + r4;
    hA[lrow][c4 * 4 + 0] = packbf(a0, a1);
    hA[lrow][c4 * 4 + 1] = packbf(a2, a3);
    hA[lrow][c4 * 4 + 2] = packbf(a4, a5);
    hA[lrow][c4 * 4 + 3] = packbf(a6, a7);
    __syncthreads();
    // ---- Phase B: C[16][128] = hA @ W2t; wave wv handles nt = wv*2, wv*2+1
    int quad = lane >> 4;
    int l16  = lane & 15;
    short8 af[4];
    #pragma unroll
    for (int kk = 0; kk < 4; ++kk) {
        const uint4* p = (const uint4*)&hA[l16][(kk * 4 + quad) * 4];
        uint4 v = *p;
        af[kk] = *(short8*)&v;
    }
    #pragma unroll
    for (int t = 0; t < 2; ++t) {
        int nt = wv * 2 + t;
        int nn2 = nt * 16 + l16;
        const uint4* Wrow = (const uint4*)(Wt + (size_t)nn2 * FDH);
        f32x4 acc = {0.f, 0.f, 0.f, 0.f};
        #pragma unroll
        for (int kk = 0; kk < 4; ++kk) {
            uint4 wvv = Wrow[kk * 4 + quad];
            short8 bf = *(short8*)&wvv;
            acc = __builtin_amdgcn_mfma_f32_16x16x32_bf16(af[kk], bf, acc, 0, 0, 0);
        }
        int row0 = nb + quad * 4;
        #pragma unroll
        for (int reg = 0; reg < 4; ++reg) {
            int r = row0 + reg;
            C[(size_t)r * FD + nt * 16 + l16] = f2bf(acc[reg]);
        }
    }
}

// ---------- CSR aggregation: uint4 gathers, 4 rows/wave, 16 rows/block ----------
__global__ __launch_bounds__(256) void aggregate_kernel(const unsigned int* Hb,
        const unsigned int* cv, const int* rowstart, const float* bias,
        unsigned int* outb) {
    int lane = threadIdx.x & 63;
    int r4   = lane >> 4;            // row within wave 0..3
    int c4   = lane & 15;            // uint4 index within 64-word row
    int wv   = threadIdx.x >> 6;
    int n = blockIdx.x * 16 + wv * 4 + r4;   // NN % 16 == 0
    const uint4* H4 = (const uint4*)Hb;
    int jb = rowstart[n], je = rowstart[n + 1];
    float a0 = 0.f, a1 = 0.f, a2 = 0.f, a3 = 0.f;
    float a4 = 0.f, a5 = 0.f, a6 = 0.f, a7 = 0.f;
    int j = jb;
    for (; j + 7 < je; j += 8) {
        unsigned int rr[8]; uint4 hh[8];
        #pragma unroll
        for (int k = 0; k < 8; ++k) rr[k] = cv[j + k];
        #pragma unroll
        for (int k = 0; k < 8; ++k) hh[k] = H4[(size_t)(rr[k] & 0xFFFFu) * 16 + c4];
        #pragma unroll
        for (int k = 0; k < 8; ++k) {
            float v = bfbits((unsigned short)(rr[k] >> 16));
            a0 += v * bflo(hh[k].x); a1 += v * bfhi(hh[k].x);
            a2 += v * bflo(hh[k].y); a3 += v * bfhi(hh[k].y);
            a4 += v * bflo(hh[k].z); a5 += v * bfhi(hh[k].z);
            a6 += v * bflo(hh[k].w); a7 += v * bfhi(hh[k].w);
        }
    }
    for (; j + 3 < je; j += 4) {
        unsigned int rr[4]; uint4 hh[4];
        #pragma unroll
        for (int k = 0; k < 4; ++k) rr[k] = cv[j + k];
        #pragma unroll
        for (int k = 0; k < 4; ++k) hh[k] = H4[(size_t)(rr[k] & 0xFFFFu) * 16 + c4];
        #pragma unroll
        for (int k = 0; k < 4; ++k) {
            float v = bfbits((unsigned short)(rr[k] >> 16));
            a0 += v * bflo(hh[k].x); a1 += v * bfhi(hh[k].x);
            a2 += v * bflo(hh[k].y); a3 += v * bfhi(hh[k].y);
            a4 += v * bflo(hh[k].z); a5 += v * bfhi(hh[k].z);
            a6 += v * bflo(hh[k].w); a7 += v * bfhi(hh[k].w);
        }
    }
    for (; j < je; ++j) {
        unsigned int r = cv[j];
        uint4 h = H4[(size_t)(r & 0xFFFFu) * 16 + c4];
        float v = bfbits((unsigned short)(r >> 16));
        a0 += v * bflo(h.x); a1 += v * bfhi(h.x);
        a2 += v * bflo(h.y); a3 += v * bfhi(h.y);
        a4 += v * bflo(h.z); a5 += v * bfhi(h.z);
        a6 += v * bflo(h.w); a7 += v * bfhi(h.w);
    }
    a0 = fmaxf(a0 + bias[8 * c4 + 0], 0.f);
    a1 = fmaxf(a1 + bias[8 * c4 + 1], 0.f);
    a2 = fmaxf(a2 + bias[8 * c4 + 2], 0.f);
    a3 = fmaxf(a3 + bias[8 * c4 + 3], 0.f);
    a4 = fmaxf(a4 + bias[8 * c4 + 4], 0.f);
    a5 = fmaxf(a5 + bias[8 * c4 + 5], 0.f);
    a6 = fmaxf(a6 + bias[8 * c4 + 6], 0.f);
    a7 = fmaxf(a7 + bias[8 * c4 + 7], 0.f);
    uint4 out;
    out.x = packbf(a0, a1);
    out.y = packbf(a2, a3);
    out.z = packbf(a4, a5);
    out.w = packbf(a6, a7);
    ((uint4*)outb)[(size_t)n * 16 + c4] = out;
}

// ---------- fused mean-pool + MLP head ----------
__global__ __launch_bounds__(256) void poolhead(const unsigned int* Hb,
        const int* gstart, const float* addf, const float* fc1w, const float* fc1b,
        const float* fc2w, const float* fc2b, const unsigned int* x, void* outp) {
    int g = blockIdx.x;
    int t = threadIdx.x;
    int q = t >> 6, w = t & 63;
    int obf = wave_probe_bf16(x, 64);
    int s = gstart[g], e = gstart[g + 1];
    float a0 = 0.f, a1 = 0.f;
    #pragma unroll 4
    for (int n = s + q; n < e; n += 4) {
        unsigned int h = Hb[(size_t)n * FDH + w];
        a0 += bflo(h);
        a1 += bfhi(h);
    }
    __shared__ float pp[4][FD];
    __shared__ float z[FD + FA];
    __shared__ float h[FD];
    pp[q][2 * w]     = a0;
    pp[q][2 * w + 1] = a1;
    __syncthreads();
    if (t < FD) {
        float cnt = (float)(e - s);
        if (cnt < 1.0f) cnt = 1.0f;
        z[t] = (pp[0][t] + pp[1][t] + pp[2][t] + pp[3][t]) / cnt;
    }
    if (t >= FD && t < FD + FA) z[t] = addf[g * FA + (t - FD)];
    __syncthreads();
    if (t < FD) {
        float acc = fc1b[t];
        #pragma unroll 4
        for (int k = 0; k < FD + FA; ++k)
            acc += z[k] * fc1w[k * FD + t];
        h[t] = fmaxf(acc, 0.f);
    }
    __syncthreads();
    if (t < 2) {
        float o = fc2b[t];
        for (int j = 0; j < FD; ++j) o += h[j] * fc2w[j * 2 + t];
        if (obf) ((unsigned short*)outp)[g * 2 + t] = f2bf(o);
        else     ((float*)outp)[g * 2 + t] = o;
    }
}

extern "C" void kernel_launch(void* const* d_in, const int* in_sizes, int n_in,
                              void* d_out, int out_size, void* d_ws, size_t ws_size,
                              hipStream_t stream) {
    (void)out_size;

    if (n_in != 12) {
        hipLaunchKernelGGL(mark_kernel, dim3(1), dim3(128), 0, stream,
                           (float*)d_out, 2000.0f);
        return;
    }
    const int exp_sizes[12] = {6400000, 1600000, 50000, 4096, 16384, 128,
                               16384, 128, 20480, 128, 256, 2};
    for (int i = 0; i < 12; ++i) {
        if (in_sizes[i] != exp_sizes[i]) {
            hipLaunchKernelGGL(mark_kernel, dim3(1), dim3(128), 0, stream,
                               (float*)d_out, 3000.0f + 100.0f * i);
            return;
        }
    }

    size_t off = 0;
    char* base = (char*)d_ws;
#define WSALLOC(ptr, type, nbytes) \
    type* ptr = (type*)(base + off); off += (((size_t)(nbytes)) + 255) & ~(size_t)255;
    WSALLOC(bufA,  unsigned int, (size_t)NN * FDH * 4)
    WSALLOC(bufB,  unsigned int, (size_t)NN * FDH * 4)
    WSALLOC(dinv,  float, (size_t)NN * 4)
    WSALLOC(degi,  int,   (size_t)NN * 4)
    WSALLOC(tsum,  int,   256 * 4)
    WSALLOC(rowst, int,   (size_t)(NN + 1) * 4)
    WSALLOC(cursor,int,   (size_t)NN * 4)
    WSALLOC(cv,    unsigned int, (size_t)EETOT * 4)
    WSALLOC(gstart,int,   (size_t)(NG + 1) * 4)
    WSALLOC(ebsd,  int2,  (size_t)NCHK * ECHK * 8)
    WSALLOC(bofs,  int,   (size_t)NCHK * 8 * 4)
    WSALLOC(W1t,   unsigned int, (size_t)FD * FDH * 4)
    WSALLOC(W2t,   unsigned int, (size_t)FD * FDH * 4)
    WSALLOC(b1f,   float, FD * 4)
    WSALLOC(b2f,   float, FD * 4)
    WSALLOC(addff, float, (size_t)NG * FA * 4)
    WSALLOC(fc1wf, float, (size_t)(FD + FA) * FD * 4)
    WSALLOC(fc1bf, float, FD * 4)
    WSALLOC(fc2wf, float, FD * 2 * 4)
    WSALLOC(fc2bf, float, 2 * 4)
#undef WSALLOC
    if (ws_size < off) {
        hipLaunchKernelGGL(mark_kernel, dim3(1), dim3(128), 0, stream,
                           (float*)d_out, 1000.0f);
        return;
    }

    const int* ei    = (const int*)d_in[1];
    const int* batch = (const int*)d_in[2];

    hipLaunchKernelGGL(prep, dim3(360), dim3(256), 0, stream,
                       d_in[3], d_in[4], d_in[5], d_in[6], d_in[7],
                       d_in[8], d_in[9], d_in[10], d_in[11],
                       W1t, W2t, addff, b1f, b2f, fc1wf, fc1bf,
                       fc2wf, fc2bf, degi, tsum);

    hipLaunchKernelGGL(bin_gemm1, dim3(NCHK + GEMMB), dim3(256), 0, stream,
                       ei, degi, ebsd, bofs,
                       d_in[0], W1t, (unsigned short*)bufA);

    hipLaunchKernelGGL(scan_fused, dim3(NBLK), dim3(256), 0, stream,
                       degi, batch, tsum, dinv, rowst, cursor, gstart);

    hipLaunchKernelGGL(fill_kernel, dim3(FILLB), dim3(256), 0, stream,
                       ebsd, bofs, dinv, cursor, cv);

    // layer 1 aggregate + layer 2 GEMM fused: bufA(H1) -> bufB(H2)
    hipLaunchKernelGGL(agg_gemm2, dim3(NN / 16), dim3(256), 0, stream,
                       bufA, cv, rowst, b1f, W2t, (unsigned short*)bufB);

    // layer 2 aggregate: bufB(H2) -> bufA (relu'd, packed)
    hipLaunchKernelGGL(aggregate_kernel, dim3(NN / 16), dim3(256), 0, stream,
                       bufB, cv, rowst, b2f, bufA);

    hipLaunchKernelGGL(poolhead, dim3(NG), dim3(256), 0, stream,
                       bufA, gstart, addff, fc1wf, fc1bf, fc2wf, fc2bf,
                       (const unsigned int*)d_in[0], d_out);
}

// Round 14
// 278.807 us; speedup vs baseline: 1.0643x; 1.0004x over previous
//
#include <hip/hip_runtime.h>

#define NN 50000
#define NE 800000
#define FD 128
#define FDH 64            // FD/2 packed bf16 pairs
#define FA 32
#define NG 128
#define EETOT (NE + NN)
#define NBLK ((NN + 255) / 256)   // 196 scan tiles
#define NPXCD 6250                // nodes per XCD-parity bin
#define ECHK 2048                 // edges per bin chunk
#define NCHK ((NE + ECHK - 1) / ECHK)   // 391 chunks
#define FPB 52                    // fill block-groups per parity
#define FILLB (8 * FPB)           // 416 fill blocks
#define GEMMB ((NN + 63) / 64)    // 782 gemm blocks

typedef __attribute__((ext_vector_type(8))) short short8;
typedef __attribute__((ext_vector_type(4))) float f32x4;

// ---------- bf16 helpers ----------
__device__ __forceinline__ float bfbits(unsigned short u) {
    return __uint_as_float(((unsigned int)u) << 16);
}
__device__ __forceinline__ float bflo(unsigned int p) { return __uint_as_float(p << 16); }
__device__ __forceinline__ float bfhi(unsigned int p) { return __uint_as_float(p & 0xffff0000u); }
__device__ __forceinline__ unsigned short f2bf(float f) {   // RNE
    unsigned int u = __float_as_uint(f);
    unsigned int r = u + 0x7FFFu + ((u >> 16) & 1u);
    return (unsigned short)(r >> 16);
}
__device__ __forceinline__ unsigned int packbf(float a, float b) {
    return (unsigned int)f2bf(a) | ((unsigned int)f2bf(b) << 16);
}

// ---------- inline wave-parallel dtype probes ----------
__device__ __forceinline__ int wave_probe_bf16(const unsigned int* t, int nwords) {
    int lane = threadIdx.x & 63;
    unsigned int wv = (lane < nwords) ? t[lane] : 0u;
    int nzp = (wv != 0u) ? 1 : 0;
    unsigned int e = (wv >> 7) & 0xFFu;
    int hitp = (nzp && e >= 100u && e <= 140u) ? 1 : 0;
    int nz = __popcll(__ballot(nzp));
    int hits = __popcll(__ballot(hitp));
    return (nz < 8) ? 1 : (hits * 4 >= nz * 3);
}
__device__ __forceinline__ int wave_probe_is64(const int* ei) {
    int lane = threadIdx.x & 63;
    int v = (lane < 32) ? ei[2 * lane + 1] : 0;
    return (__ballot(v != 0) == 0ull) ? 1 : 0;
}

// ---------- sentinels ----------
__global__ __launch_bounds__(128) void mark_kernel(float* out, float v) {
    out[threadIdx.x] = v;
}

// ---------- prep: weights + params + zero {degi,tsum} ----------
__global__ __launch_bounds__(256) void prep(
        const void* addf, const void* w1, const void* b1, const void* w2,
        const void* b2, const void* fc1w, const void* fc1b, const void* fc2w,
        const void* fc2b, unsigned int* W1t, unsigned int* W2t,
        float* addff, float* b1f, float* b2f, float* fc1wf, float* fc1bf,
        float* fc2wf, float* fc2bf, int* degi, int* tsum) {
    int b = blockIdx.x;
    if (b < 64) {
        int rel = b * 256 + threadIdx.x;             // [0,16384)
        const void* src = (rel < 8192) ? w1 : w2;
        unsigned int* dst = (rel < 8192) ? W1t : W2t;
        int flag = wave_probe_bf16((const unsigned int*)src, 64);
        int rr = rel & 8191;
        int n = rr >> 6, kk = rr & 63;
        float lo, hi;
        if (flag) {
            const unsigned short* s = (const unsigned short*)src;
            lo = bfbits(s[(2 * kk) * FD + n]);
            hi = bfbits(s[(2 * kk + 1) * FD + n]);
        } else {
            const float* s = (const float*)src;
            lo = s[(2 * kk) * FD + n];
            hi = s[(2 * kk + 1) * FD + n];
        }
        dst[rr] = packbf(lo, hi);
    } else if (b < 163) {
        int i = (b - 64) * 256 + threadIdx.x;        // [0,25344)
        int wb = (b - 64) * 256 + (threadIdx.x & ~63);  // wave base
        const void* src; float* dst; int base; int prnw; int lim;
        if      (wb < 4096)  { src = addf; dst = addff; base = 0;     prnw = 64; lim = 4096;  }
        else if (wb < 4224)  { src = b1;   dst = b1f;   base = 4096;  prnw = 64; lim = 128;   }
        else if (wb < 4352)  { src = b2;   dst = b2f;   base = 4224;  prnw = 64; lim = 128;   }
        else if (wb < 24832) { src = fc1w; dst = fc1wf; base = 4352;  prnw = 64; lim = 20480; }
        else if (wb < 24960) { src = fc1b; dst = fc1bf; base = 24832; prnw = 64; lim = 128;   }
        else if (wb < 25216) { src = fc2w; dst = fc2wf; base = 24960; prnw = 64; lim = 256;   }
        else if (wb < 25280) { src = fc2b; dst = fc2bf; base = 25216; prnw = 1;  lim = 2;     }
        else return;
        int flag = wave_probe_bf16((const unsigned int*)src, prnw);
        int rel = i - base;
        if (rel < lim) {
            if (flag) dst[rel] = bfbits(((const unsigned short*)src)[rel]);
            else      dst[rel] = ((const float*)src)[rel];
        }
    } else {
        int i = (b - 163) * 256 + threadIdx.x;
        if      (i < NN)       degi[i] = 0;
        else if (i < NN + 256) tsum[i - NN] = 0;
    }
}

// ---------- merged: chunk-binning (blocks < NCHK) + LDS-staged GEMM1 -------------
// gemm1 half: cooperative coalesced x-tile load -> bf16 LDS [64][68] (2-way banks,
// free) -> per-lane MFMA fragments from LDS -> C tile back through LDS -> coalesced
// uint2 row stores. Same f2bf/MFMA order as before -> bit-identical.
__global__ __launch_bounds__(256) void bin_gemm1(const int* ei, int* deg,
        int2* ebsd, int* bofs,
        const void* __restrict__ Av, const unsigned int* __restrict__ Wt,
        unsigned short* __restrict__ C) {
    __shared__ unsigned int hA[64][68];
    if ((int)blockIdx.x < NCHK) {
        __shared__ int cnt[8];
        __shared__ int sbase[8];
        int is64 = wave_probe_is64(ei);
        int chunk = blockIdx.x;
        int e0 = chunk * ECHK;
        int nedge = NE - e0; if (nedge > ECHK) nedge = ECHK;
        if (threadIdx.x < 8) cnt[threadIdx.x] = 0;
        __syncthreads();
        int sA[8], dA[8], rk[8], pr[8];
        #pragma unroll
        for (int k = 0; k < 8; ++k) {
            int j = k * 256 + threadIdx.x;
            pr[k] = -1;
            if (j < nedge) {
                int e = e0 + j;
                int s = is64 ? ei[2 * e] : ei[e];
                int d = is64 ? ei[2 * (NE + e)] : ei[NE + e];
                atomicAdd(&deg[d], 1);          // spread over 50K addrs: cheap
                int p = d / NPXCD;
                sA[k] = s; dA[k] = d; pr[k] = p;
                rk[k] = atomicAdd(&cnt[p], 1);  // LDS atomic: on-CU, fast
            }
        }
        __syncthreads();
        if (threadIdx.x == 0) {
            int acc = 0;
            #pragma unroll
            for (int p = 0; p < 8; ++p) {
                sbase[p] = acc;
                bofs[chunk * 8 + p] = acc;
                acc += cnt[p];
            }
        }
        __syncthreads();
        #pragma unroll
        for (int k = 0; k < 8; ++k) {
            if (pr[k] >= 0) {
                int idx = chunk * ECHK + sbase[pr[k]] + rk[k];
                ebsd[idx] = make_int2(sA[k], dA[k]);
            }
        }
        return;
    }
    // ---- gemm1: C[64-row tile] = toBF16(x) @ W1t, LDS-staged ----
    int bid = blockIdx.x - NCHK;
    int mbase = bid * 64;
    bool f32in = !wave_probe_bf16((const unsigned int*)Av, 64);
    if (!f32in) {
        const unsigned int* xb = (const unsigned int*)Av;
        for (int i = threadIdx.x; i < 64 * 64; i += 256) {
            int row = i >> 6, w = i & 63;
            int gr = mbase + row; if (gr >= NN) gr = NN - 1;
            hA[row][w] = xb[(size_t)gr * 64 + w];
        }
    } else {
        const float2* xf2 = (const float2*)Av;
        for (int i = threadIdx.x; i < 64 * 64; i += 256) {
            int row = i >> 6, w = i & 63;
            int gr = mbase + row; if (gr >= NN) gr = NN - 1;
            float2 f = xf2[(size_t)gr * 64 + w];
            hA[row][w] = packbf(f.x, f.y);
        }
    }
    __syncthreads();
    int wave = threadIdx.x >> 6;
    int lane = threadIdx.x & 63;
    int quad = lane >> 4;
    int l16  = lane & 15;
    int lrow = wave * 16 + l16;
    short8 af[4];
    #pragma unroll
    for (int kk = 0; kk < 4; ++kk) {
        uint4 v = *(const uint4*)&hA[lrow][(kk * 4 + quad) * 4];
        af[kk] = *(short8*)&v;
    }
    __syncthreads();          // all waves done reading A before hA reused for C
    f32x4 accs[8];
    #pragma unroll
    for (int nt = 0; nt < 8; ++nt) {
        int n = nt * 16 + l16;
        const uint4* Wrow = (const uint4*)(Wt + (size_t)n * FDH);
        f32x4 acc = {0.f, 0.f, 0.f, 0.f};
        #pragma unroll
        for (int kk = 0; kk < 4; ++kk) {
            uint4 wv = Wrow[kk * 4 + quad];
            short8 bf = *(short8*)&wv;
            acc = __builtin_amdgcn_mfma_f32_16x16x32_bf16(af[kk], bf, acc, 0, 0, 0);
        }
        accs[nt] = acc;
    }
    unsigned short* hs = (unsigned short*)hA;   // pitch 136 ushorts (= 68 uints)
    #pragma unroll
    for (int nt = 0; nt < 8; ++nt) {
        #pragma unroll
        for (int reg = 0; reg < 4; ++reg) {
            int row = wave * 16 + quad * 4 + reg;
            hs[row * 136 + nt * 16 + l16] = f2bf(accs[nt][reg]);
        }
    }
    __syncthreads();
    for (int i = threadIdx.x; i < 64 * 32; i += 256) {   // 64 rows x 32 uint2
        int row = i >> 5, q = i & 31;
        int gr = mbase + row;
        if (gr < NN)
            ((uint2*)C)[(size_t)gr * 32 + q] = ((const uint2*)&hs[row * 136])[q];
    }
}

// ---------- fused scan: standalone ----------
__global__ __launch_bounds__(256) void scan_fused(const int* degi, const int* batch,
        int* tsum, float* dinv, int* rowstart, int* cursor, int* gstart) {
    __shared__ int sh[256];
    int b = blockIdx.x, t = threadIdx.x;
    int i = b * 256 + t;
    int d = (i < NN) ? degi[i] : 0;
    if (i < NN) dinv[i] = rsqrtf((float)(d + 1));
    int v = (i < NN) ? d + 1 : 0;
    sh[t] = v;
    __syncthreads();
    for (int off = 1; off < 256; off <<= 1) {
        int a = (t >= off) ? sh[t - off] : 0;
        __syncthreads();
        sh[t] += a;
        __syncthreads();
    }
    int incl = sh[t];
    int total = sh[255];
    if (t == 0) atomicExch(&tsum[b], total);   // publish first; total >= 80 > 0
    int pt = 0;
    for (int j = t; j < b; j += 256) {
        int s;
        do { s = atomicAdd(&tsum[j], 0); } while (s == 0);
        pt += s;
    }
    __syncthreads();
    sh[t] = pt;
    __syncthreads();
    for (int off = 128; off >= 1; off >>= 1) {
        if (t < off) sh[t] += sh[t + off];
        __syncthreads();
    }
    int boff = sh[0];
    if (i < NN) {
        int r = boff + incl - v;
        rowstart[i] = r;
        cursor[i]   = r;
    }
    if (i == 0) rowstart[NN] = EETOT;
    if (i < NN) {
        int is64 = (batch[NN - 1] == 0) ? 1 : 0;
        int bc = is64 ? batch[2 * i] : batch[i];
        if (i == 0) {
            for (int g = 0; g <= bc; ++g) gstart[g] = 0;
        } else {
            int bp = is64 ? batch[2 * (i - 1)] : batch[i - 1];
            for (int g = bp + 1; g <= bc; ++g) gstart[g] = i;
        }
        if (i == NN - 1) {
            for (int g = bc + 1; g <= NG; ++g) gstart[g] = NN;
        }
    }
}

// ---------- binned CSR fill (standalone: cv lines stay L2-resident) ----------
__global__ __launch_bounds__(256) void fill_kernel(const int2* ebsd, const int* bofs,
        const float* dinv, int* cursor, unsigned int* cv) {
    int par = blockIdx.x & 7;        // matches XCD round-robin
    int g   = blockIdx.x >> 3;       // group within parity [0,FPB)
    for (int chunk = g; chunk < NCHK; chunk += FPB) {
        int b0 = bofs[chunk * 8 + par];
        int nedge = NE - chunk * ECHK; if (nedge > ECHK) nedge = ECHK;
        int b1 = (par < 7) ? bofs[chunk * 8 + par + 1] : nedge;
        for (int j = b0 + (int)threadIdx.x; j < b1; j += 256) {
            int2 sd = ebsd[chunk * ECHK + j];
            int pos = atomicAdd(&cursor[sd.y], 1);
            cv[pos] = (unsigned int)sd.x
                    | ((unsigned int)f2bf(dinv[sd.x] * dinv[sd.y]) << 16);
        }
    }
    // self-loops for this parity's node range
    for (int n = par * NPXCD + g * 256 + threadIdx.x; n < (par + 1) * NPXCD;
         n += FPB * 256) {
        int pos = atomicAdd(&cursor[n], 1);
        float di = dinv[n];
        cv[pos] = (unsigned int)n | ((unsigned int)f2bf(di * di) << 16);
    }
}

// ---------- fused: agg layer1 (Phase A) + GEMM2 (Phase B), block = 16 nodes ------
__global__ __launch_bounds__(256) void agg_gemm2(const unsigned int* Hb,
        const unsigned int* cv, const int* rowstart, const float* bias,
        const unsigned int* __restrict__ Wt, unsigned short* __restrict__ C) {
    __shared__ unsigned int hA[16][68];   // 16 rows x 64 uints, +4 pad
    int lane = threadIdx.x & 63;
    int r4   = lane >> 4;
    int c4   = lane & 15;
    int wv   = threadIdx.x >> 6;
    int nb = blockIdx.x * 16;            // NN % 16 == 0
    int n = nb + wv * 4 + r4;
    const uint4* H4 = (const uint4*)Hb;
    int jb = rowstart[n], je = rowstart[n + 1];
    float a0 = 0.f, a1 = 0.f, a2 = 0.f, a3 = 0.f;
    float a4 = 0.f, a5 = 0.f, a6 = 0.f, a7 = 0.f;
    int j = jb;
    for (; j + 7 < je; j += 8) {
        unsigned int rr[8]; uint4 hh[8];
        #pragma unroll
        for (int k = 0; k < 8; ++k) rr[k] = cv[j + k];
        #pragma unroll
        for (int k = 0; k < 8; ++k) hh[k] = H4[(size_t)(rr[k] & 0xFFFFu) * 16 + c4];
        #pragma unroll
        for (int k = 0; k < 8; ++k) {
            float v = bfbits((unsigned short)(rr[k] >> 16));
            a0 += v * bflo(hh[k].x); a1 += v * bfhi(hh[k].x);
            a2 += v * bflo(hh[k].y); a3 += v * bfhi(hh[k].y);
            a4 += v * bflo(hh[k].z); a5 += v * bfhi(hh[k].z);
            a6 += v * bflo(hh[k].w); a7 += v * bfhi(hh[k].w);
        }
    }
    for (; j + 3 < je; j += 4) {
        unsigned int rr[4]; uint4 hh[4];
        #pragma unroll
        for (int k = 0; k < 4; ++k) rr[k] = cv[j + k];
        #pragma unroll
        for (int k = 0; k < 4; ++k) hh[k] = H4[(size_t)(rr[k] & 0xFFFFu) * 16 + c4];
        #pragma unroll
        for (int k = 0; k < 4; ++k) {
            float v = bfbits((unsigned short)(rr[k] >> 16));
            a0 += v * bflo(hh[k].x); a1 += v * bfhi(hh[k].x);
            a2 += v * bflo(hh[k].y); a3 += v * bfhi(hh[k].y);
            a4 += v * bflo(hh[k].z); a5 += v * bfhi(hh[k].z);
            a6 += v * bflo(hh[k].w); a7 += v * bfhi(hh[k].w);
        }
    }
    for (; j < je; ++j) {
        unsigned int r = cv[j];
        uint4 h = H4[(size_t)(r & 0xFFFFu) * 16 + c4];
        float v = bfbits((unsigned short)(r >> 16));
        a0 += v * bflo(h.x); a1 += v * bfhi(h.x);
        a2 += v * bflo(h.y); a3 += v * bfhi(h.y);
        a4 += v * bflo(h.z); a5 += v * bfhi(h.z);
        a6 += v * bflo(h.w); a7 += v * bfhi(h.w);
    }
    a0 = fmaxf(a0 + bias[8 * c4 + 0], 0.f);
    a1 = fmaxf(a1 + bias[8 * c4 + 1], 0.f);
    a2 = fmaxf(a2 + bias[8 * c4 + 2], 0.f);
    a3 = fmaxf(a3 + bias[8 * c4 + 3], 0.f);
    a4 = fmaxf(a4 + bias[8 * c4 + 4], 0.f);
    a5 = fmaxf(a5 + bias[8 * c4 + 5], 0.f);
    a6 = fmaxf(a6 + bias[8 * c4 + 6], 0.f);
    a7 = fmaxf(a7 + bias[8 * c4 + 7], 0.f);
    int lrow = wv * 4 + r4;
    hA[lrow][c4 * 4 + 0] = packbf(a0, a1);
    hA[lrow][c4 * 4 + 1] = packbf(a2, a3);
    hA[lrow][c4 * 4 + 2] = packbf(a4, a5);
    hA[lrow][c4 * 4 + 3] = packbf(a6, a7);
    __syncthreads();
    // ---- Phase B: C[16][128] = hA @ W2t; wave wv handles nt = wv*2, wv*2+1
    int quad = lane >> 4;
    int l16  = lane & 15;
    short8 af[4];
    #pragma unroll
    for (int kk = 0; kk < 4; ++kk) {
        const uint4* p = (const uint4*)&hA[l16][(kk * 4 + quad) * 4];
        uint4 v = *p;
        af[kk] = *(short8*)&v;
    }
    #pragma unroll
    for (int t = 0; t < 2; ++t) {
        int nt = wv * 2 + t;
        int nn2 = nt * 16 + l16;
        const uint4* Wrow = (const uint4*)(Wt + (size_t)nn2 * FDH);
        f32x4 acc = {0.f, 0.f, 0.f, 0.f};
        #pragma unroll
        for (int kk = 0; kk < 4; ++kk) {
            uint4 wvv = Wrow[kk * 4 + quad];
            short8 bf = *(short8*)&wvv;
            acc = __builtin_amdgcn_mfma_f32_16x16x32_bf16(af[kk], bf, acc, 0, 0, 0);
        }
        int row0 = nb + quad * 4;
        #pragma unroll
        for (int reg = 0; reg < 4; ++reg) {
            int r = row0 + reg;
            C[(size_t)r * FD + nt * 16 + l16] = f2bf(acc[reg]);
        }
    }
}

// ---------- CSR aggregation: uint4 gathers, 4 rows/wave, 16 rows/block ----------
__global__ __launch_bounds__(256) void aggregate_kernel(const unsigned int* Hb,
        const unsigned int* cv, const int* rowstart, const float* bias,
        unsigned int* outb) {
    int lane = threadIdx.x & 63;
    int r4   = lane >> 4;            // row within wave 0..3
    int c4   = lane & 15;            // uint4 index within 64-word row
    int wv   = threadIdx.x >> 6;
    int n = blockIdx.x * 16 + wv * 4 + r4;   // NN % 16 == 0
    const uint4* H4 = (const uint4*)Hb;
    int jb = rowstart[n], je = rowstart[n + 1];
    float a0 = 0.f, a1 = 0.f, a2 = 0.f, a3 = 0.f;
    float a4 = 0.f, a5 = 0.f, a6 = 0.f, a7 = 0.f;
    int j = jb;
    for (; j + 7 < je; j += 8) {
        unsigned int rr[8]; uint4 hh[8];
        #pragma unroll
        for (int k = 0; k < 8; ++k) rr[k] = cv[j + k];
        #pragma unroll
        for (int k = 0; k < 8; ++k) hh[k] = H4[(size_t)(rr[k] & 0xFFFFu) * 16 + c4];
        #pragma unroll
        for (int k = 0; k < 8; ++k) {
            float v = bfbits((unsigned short)(rr[k] >> 16));
            a0 += v * bflo(hh[k].x); a1 += v * bfhi(hh[k].x);
            a2 += v * bflo(hh[k].y); a3 += v * bfhi(hh[k].y);
            a4 += v * bflo(hh[k].z); a5 += v * bfhi(hh[k].z);
            a6 += v * bflo(hh[k].w); a7 += v * bfhi(hh[k].w);
        }
    }
    for (; j + 3 < je; j += 4) {
        unsigned int rr[4]; uint4 hh[4];
        #pragma unroll
        for (int k = 0; k < 4; ++k) rr[k] = cv[j + k];
        #pragma unroll
        for (int k = 0; k < 4; ++k) hh[k] = H4[(size_t)(rr[k] & 0xFFFFu) * 16 + c4];
        #pragma unroll
        for (int k = 0; k < 4; ++k) {
            float v = bfbits((unsigned short)(rr[k] >> 16));
            a0 += v * bflo(hh[k].x); a1 += v * bfhi(hh[k].x);
            a2 += v * bflo(hh[k].y); a3 += v * bfhi(hh[k].y);
            a4 += v * bflo(hh[k].z); a5 += v * bfhi(hh[k].z);
            a6 += v * bflo(hh[k].w); a7 += v * bfhi(hh[k].w);
        }
    }
    for (; j < je; ++j) {
        unsigned int r = cv[j];
        uint4 h = H4[(size_t)(r & 0xFFFFu) * 16 + c4];
        float v = bfbits((unsigned short)(r >> 16));
        a0 += v * bflo(h.x); a1 += v * bfhi(h.x);
        a2 += v * bflo(h.y); a3 += v * bfhi(h.y);
        a4 += v * bflo(h.z); a5 += v * bfhi(h.z);
        a6 += v * bflo(h.w); a7 += v * bfhi(h.w);
    }
    a0 = fmaxf(a0 + bias[8 * c4 + 0], 0.f);
    a1 = fmaxf(a1 + bias[8 * c4 + 1], 0.f);
    a2 = fmaxf(a2 + bias[8 * c4 + 2], 0.f);
    a3 = fmaxf(a3 + bias[8 * c4 + 3], 0.f);
    a4 = fmaxf(a4 + bias[8 * c4 + 4], 0.f);
    a5 = fmaxf(a5 + bias[8 * c4 + 5], 0.f);
    a6 = fmaxf(a6 + bias[8 * c4 + 6], 0.f);
    a7 = fmaxf(a7 + bias[8 * c4 + 7], 0.f);
    uint4 out;
    out.x = packbf(a0, a1);
    out.y = packbf(a2, a3);
    out.z = packbf(a4, a5);
    out.w = packbf(a6, a7);
    ((uint4*)outb)[(size_t)n * 16 + c4] = out;
}

// ---------- fused mean-pool + MLP head ----------
__global__ __launch_bounds__(256) void poolhead(const unsigned int* Hb,
        const int* gstart, const float* addf, const float* fc1w, const float* fc1b,
        const float* fc2w, const float* fc2b, const unsigned int* x, void* outp) {
    int g = blockIdx.x;
    int t = threadIdx.x;
    int q = t >> 6, w = t & 63;
    int obf = wave_probe_bf16(x, 64);
    int s = gstart[g], e = gstart[g + 1];
    float a0 = 0.f, a1 = 0.f;
    #pragma unroll 4
    for (int n = s + q; n < e; n += 4) {
        unsigned int h = Hb[(size_t)n * FDH + w];
        a0 += bflo(h);
        a1 += bfhi(h);
    }
    __shared__ float pp[4][FD];
    __shared__ float z[FD + FA];
    __shared__ float h[FD];
    pp[q][2 * w]     = a0;
    pp[q][2 * w + 1] = a1;
    __syncthreads();
    if (t < FD) {
        float cnt = (float)(e - s);
        if (cnt < 1.0f) cnt = 1.0f;
        z[t] = (pp[0][t] + pp[1][t] + pp[2][t] + pp[3][t]) / cnt;
    }
    if (t >= FD && t < FD + FA) z[t] = addf[g * FA + (t - FD)];
    __syncthreads();
    if (t < FD) {
        float acc = fc1b[t];
        #pragma unroll 4
        for (int k = 0; k < FD + FA; ++k)
            acc += z[k] * fc1w[k * FD + t];
        h[t] = fmaxf(acc, 0.f);
    }
    __syncthreads();
    if (t < 2) {
        float o = fc2b[t];
        for (int j = 0; j < FD; ++j) o += h[j] * fc2w[j * 2 + t];
        if (obf) ((unsigned short*)outp)[g * 2 + t] = f2bf(o);
        else     ((float*)outp)[g * 2 + t] = o;
    }
}

extern "C" void kernel_launch(void* const* d_in, const int* in_sizes, int n_in,
                              void* d_out, int out_size, void* d_ws, size_t ws_size,
                              hipStream_t stream) {
    (void)out_size;

    if (n_in != 12) {
        hipLaunchKernelGGL(mark_kernel, dim3(1), dim3(128), 0, stream,
                           (float*)d_out, 2000.0f);
        return;
    }
    const int exp_sizes[12] = {6400000, 1600000, 50000, 4096, 16384, 128,
                               16384, 128, 20480, 128, 256, 2};
    for (int i = 0; i < 12; ++i) {
        if (in_sizes[i] != exp_sizes[i]) {
            hipLaunchKernelGGL(mark_kernel, dim3(1), dim3(128), 0, stream,
                               (float*)d_out, 3000.0f + 100.0f * i);
            return;
        }
    }

    size_t off = 0;
    char* base = (char*)d_ws;
#define WSALLOC(ptr, type, nbytes) \
    type* ptr = (type*)(base + off); off += (((size_t)(nbytes)) + 255) & ~(size_t)255;
    WSALLOC(bufA,  unsigned int, (size_t)NN * FDH * 4)
    WSALLOC(bufB,  unsigned int, (size_t)NN * FDH * 4)
    WSALLOC(dinv,  float, (size_t)NN * 4)
    WSALLOC(degi,  int,   (size_t)NN * 4)
    WSALLOC(tsum,  int,   256 * 4)
    WSALLOC(rowst, int,   (size_t)(NN + 1) * 4)
    WSALLOC(cursor,int,   (size_t)NN * 4)
    WSALLOC(cv,    unsigned int, (size_t)EETOT * 4)
    WSALLOC(gstart,int,   (size_t)(NG + 1) * 4)
    WSALLOC(ebsd,  int2,  (size_t)NCHK * ECHK * 8)
    WSALLOC(bofs,  int,   (size_t)NCHK * 8 * 4)
    WSALLOC(W1t,   unsigned int, (size_t)FD * FDH * 4)
    WSALLOC(W2t,   unsigned int, (size_t)FD * FDH * 4)
    WSALLOC(b1f,   float, FD * 4)
    WSALLOC(b2f,   float, FD * 4)
    WSALLOC(addff, float, (size_t)NG * FA * 4)
    WSALLOC(fc1wf, float, (size_t)(FD + FA) * FD * 4)
    WSALLOC(fc1bf, float, FD * 4)
    WSALLOC(fc2wf, float, FD * 2 * 4)
    WSALLOC(fc2bf, float, 2 * 4)
#undef WSALLOC
    if (ws_size < off) {
        hipLaunchKernelGGL(mark_kernel, dim3(1), dim3(128), 0, stream,
                           (float*)d_out, 1000.0f);
        return;
    }

    const int* ei    = (const int*)d_in[1];
    const int* batch = (const int*)d_in[2];

    hipLaunchKernelGGL(prep, dim3(360), dim3(256), 0, stream,
                       d_in[3], d_in[4], d_in[5], d_in[6], d_in[7],
                       d_in[8], d_in[9], d_in[10], d_in[11],
                       W1t, W2t, addff, b1f, b2f, fc1wf, fc1bf,
                       fc2wf, fc2bf, degi, tsum);

    hipLaunchKernelGGL(bin_gemm1, dim3(NCHK + GEMMB), dim3(256), 0, stream,
                       ei, degi, ebsd, bofs,
                       d_in[0], W1t, (unsigned short*)bufA);

    hipLaunchKernelGGL(scan_fused, dim3(NBLK), dim3(256), 0, stream,
                       degi, batch, tsum, dinv, rowst, cursor, gstart);

    hipLaunchKernelGGL(fill_kernel, dim3(FILLB), dim3(256), 0, stream,
                       ebsd, bofs, dinv, cursor, cv);

    // layer 1 aggregate + layer 2 GEMM fused: bufA(H1) -> bufB(H2)
    hipLaunchKernelGGL(agg_gemm2, dim3(NN / 16), dim3(256), 0, stream,
                       bufA, cv, rowst, b1f, W2t, (unsigned short*)bufB);

    // layer 2 aggregate: bufB(H2) -> bufA (relu'd, packed)
    hipLaunchKernelGGL(aggregate_kernel, dim3(NN / 16), dim3(256), 0, stream,
                       bufB, cv, rowst, b2f, bufA);

    hipLaunchKernelGGL(poolhead, dim3(NG), dim3(256), 0, stream,
                       bufA, gstart, addff, fc1wf, fc1bf, fc2wf, fc2bf,
                       (const unsigned int*)d_in[0], d_out);
}

// Round 15
// 275.079 us; speedup vs baseline: 1.0788x; 1.0136x over previous
//
#include <hip/hip_runtime.h>

#define NN 50000
#define NE 800000
#define FD 128
#define FDH 64            // FD/2 packed bf16 pairs
#define FA 32
#define NG 128
#define EETOT (NE + NN)
#define NBLK ((NN + 255) / 256)   // 196 scan tiles
#define NPXCD 6250                // nodes per XCD-parity bin
#define ECHK 2048                 // edges per bin chunk
#define NCHK ((NE + ECHK - 1) / ECHK)   // 391 chunks
#define FPB 52                    // fill/deg block-groups per parity
#define FILLB (8 * FPB)           // 416 parity blocks
#define GEMMB ((NN + 63) / 64)    // 782 gemm blocks
#define PREPB 360                 // prep blocks before bin section

typedef __attribute__((ext_vector_type(8))) short short8;
typedef __attribute__((ext_vector_type(4))) float f32x4;

// ---------- bf16 helpers ----------
__device__ __forceinline__ float bfbits(unsigned short u) {
    return __uint_as_float(((unsigned int)u) << 16);
}
__device__ __forceinline__ float bflo(unsigned int p) { return __uint_as_float(p << 16); }
__device__ __forceinline__ float bfhi(unsigned int p) { return __uint_as_float(p & 0xffff0000u); }
__device__ __forceinline__ unsigned short f2bf(float f) {   // RNE
    unsigned int u = __float_as_uint(f);
    unsigned int r = u + 0x7FFFu + ((u >> 16) & 1u);
    return (unsigned short)(r >> 16);
}
__device__ __forceinline__ unsigned int packbf(float a, float b) {
    return (unsigned int)f2bf(a) | ((unsigned int)f2bf(b) << 16);
}

// ---------- inline wave-parallel dtype probes ----------
__device__ __forceinline__ int wave_probe_bf16(const unsigned int* t, int nwords) {
    int lane = threadIdx.x & 63;
    unsigned int wv = (lane < nwords) ? t[lane] : 0u;
    int nzp = (wv != 0u) ? 1 : 0;
    unsigned int e = (wv >> 7) & 0xFFu;
    int hitp = (nzp && e >= 100u && e <= 140u) ? 1 : 0;
    int nz = __popcll(__ballot(nzp));
    int hits = __popcll(__ballot(hitp));
    return (nz < 8) ? 1 : (hits * 4 >= nz * 3);
}
__device__ __forceinline__ int wave_probe_is64(const int* ei) {
    int lane = threadIdx.x & 63;
    int v = (lane < 32) ? ei[2 * lane + 1] : 0;
    return (__ballot(v != 0) == 0ull) ? 1 : 0;
}

// ---------- sentinels ----------
__global__ __launch_bounds__(128) void mark_kernel(float* out, float v) {
    out[threadIdx.x] = v;
}

// ---------- merged prep (weights/params + zero degi/tsum) + streaming bin --------
// bin no longer does deg atomics -> no hazard with prep's degi zeroing (separate
// blocks, degi only written by zeroing blocks; deg counting happens next dispatch).
__global__ __launch_bounds__(256) void prep_bin(
        const void* addf, const void* w1, const void* b1, const void* w2,
        const void* b2, const void* fc1w, const void* fc1b, const void* fc2w,
        const void* fc2b, unsigned int* W1t, unsigned int* W2t,
        float* addff, float* b1f, float* b2f, float* fc1wf, float* fc1bf,
        float* fc2wf, float* fc2bf, int* degi, int* tsum,
        const int* ei, int2* ebsd, int* bofs) {
    int b = blockIdx.x;
    if (b < 64) {
        int rel = b * 256 + threadIdx.x;             // [0,16384)
        const void* src = (rel < 8192) ? w1 : w2;
        unsigned int* dst = (rel < 8192) ? W1t : W2t;
        int flag = wave_probe_bf16((const unsigned int*)src, 64);
        int rr = rel & 8191;
        int n = rr >> 6, kk = rr & 63;
        float lo, hi;
        if (flag) {
            const unsigned short* s = (const unsigned short*)src;
            lo = bfbits(s[(2 * kk) * FD + n]);
            hi = bfbits(s[(2 * kk + 1) * FD + n]);
        } else {
            const float* s = (const float*)src;
            lo = s[(2 * kk) * FD + n];
            hi = s[(2 * kk + 1) * FD + n];
        }
        dst[rr] = packbf(lo, hi);
        return;
    } else if (b < 163) {
        int i = (b - 64) * 256 + threadIdx.x;        // [0,25344)
        int wb = (b - 64) * 256 + (threadIdx.x & ~63);  // wave base
        const void* src; float* dst; int base; int prnw; int lim;
        if      (wb < 4096)  { src = addf; dst = addff; base = 0;     prnw = 64; lim = 4096;  }
        else if (wb < 4224)  { src = b1;   dst = b1f;   base = 4096;  prnw = 64; lim = 128;   }
        else if (wb < 4352)  { src = b2;   dst = b2f;   base = 4224;  prnw = 64; lim = 128;   }
        else if (wb < 24832) { src = fc1w; dst = fc1wf; base = 4352;  prnw = 64; lim = 20480; }
        else if (wb < 24960) { src = fc1b; dst = fc1bf; base = 24832; prnw = 64; lim = 128;   }
        else if (wb < 25216) { src = fc2w; dst = fc2wf; base = 24960; prnw = 64; lim = 256;   }
        else if (wb < 25280) { src = fc2b; dst = fc2bf; base = 25216; prnw = 1;  lim = 2;     }
        else return;
        int flag = wave_probe_bf16((const unsigned int*)src, prnw);
        int rel = i - base;
        if (rel < lim) {
            if (flag) dst[rel] = bfbits(((const unsigned short*)src)[rel]);
            else      dst[rel] = ((const float*)src)[rel];
        }
        return;
    } else if (b < PREPB) {
        int i = (b - 163) * 256 + threadIdx.x;
        if      (i < NN)       degi[i] = 0;
        else if (i < NN + 256) tsum[i - NN] = 0;
        return;
    }
    // ---- streaming bin: chunk-local parity sort, LDS ranks, NO deg atomics ----
    __shared__ int cnt[8];
    __shared__ int sbase[8];
    int is64 = wave_probe_is64(ei);
    int chunk = b - PREPB;
    int e0 = chunk * ECHK;
    int nedge = NE - e0; if (nedge > ECHK) nedge = ECHK;
    if (threadIdx.x < 8) cnt[threadIdx.x] = 0;
    __syncthreads();
    int sA[8], dA[8], rk[8], pr[8];
    #pragma unroll
    for (int k = 0; k < 8; ++k) {
        int j = k * 256 + threadIdx.x;
        pr[k] = -1;
        if (j < nedge) {
            int e = e0 + j;
            int s = is64 ? ei[2 * e] : ei[e];
            int d = is64 ? ei[2 * (NE + e)] : ei[NE + e];
            int p = d / NPXCD;
            sA[k] = s; dA[k] = d; pr[k] = p;
            rk[k] = atomicAdd(&cnt[p], 1);  // LDS atomic: on-CU, fast
        }
    }
    __syncthreads();
    if (threadIdx.x == 0) {
        int acc = 0;
        #pragma unroll
        for (int p = 0; p < 8; ++p) {
            sbase[p] = acc;
            bofs[chunk * 8 + p] = acc;
            acc += cnt[p];
        }
    }
    __syncthreads();
    #pragma unroll
    for (int k = 0; k < 8; ++k) {
        if (pr[k] >= 0) {
            int idx = chunk * ECHK + sbase[pr[k]] + rk[k];
            ebsd[idx] = make_int2(sA[k], dA[k]);
        }
    }
}

// ---------- merged: parity-local degree (blocks < FILLB) + LDS-staged GEMM1 ------
// deg-half mirrors fill's parity partitioning: every atomicAdd for a given degi
// line originates from ONE parity (one XCD) -> L2-local RMW, no cross-XCD
// ping-pong. gemm1-half: coalesced x-tile -> LDS -> MFMA -> coalesced C stores.
__global__ __launch_bounds__(256) void deg_gemm1(const int2* ebsd, const int* bofs,
        int* degi,
        const void* __restrict__ Av, const unsigned int* __restrict__ Wt,
        unsigned short* __restrict__ C) {
    __shared__ unsigned int hA[64][68];
    if ((int)blockIdx.x < FILLB) {
        int par = blockIdx.x & 7;
        int g   = blockIdx.x >> 3;
        for (int chunk = g; chunk < NCHK; chunk += FPB) {
            int b0 = bofs[chunk * 8 + par];
            int nedge = NE - chunk * ECHK; if (nedge > ECHK) nedge = ECHK;
            int b1 = (par < 7) ? bofs[chunk * 8 + par + 1] : nedge;
            for (int j = b0 + (int)threadIdx.x; j < b1; j += 256) {
                int2 sd = ebsd[chunk * ECHK + j];
                atomicAdd(&degi[sd.y], 1);
            }
        }
        return;
    }
    // ---- gemm1: C[64-row tile] = toBF16(x) @ W1t, LDS-staged ----
    int bid = blockIdx.x - FILLB;
    int mbase = bid * 64;
    bool f32in = !wave_probe_bf16((const unsigned int*)Av, 64);
    if (!f32in) {
        const unsigned int* xb = (const unsigned int*)Av;
        for (int i = threadIdx.x; i < 64 * 64; i += 256) {
            int row = i >> 6, w = i & 63;
            int gr = mbase + row; if (gr >= NN) gr = NN - 1;
            hA[row][w] = xb[(size_t)gr * 64 + w];
        }
    } else {
        const float2* xf2 = (const float2*)Av;
        for (int i = threadIdx.x; i < 64 * 64; i += 256) {
            int row = i >> 6, w = i & 63;
            int gr = mbase + row; if (gr >= NN) gr = NN - 1;
            float2 f = xf2[(size_t)gr * 64 + w];
            hA[row][w] = packbf(f.x, f.y);
        }
    }
    __syncthreads();
    int wave = threadIdx.x >> 6;
    int lane = threadIdx.x & 63;
    int quad = lane >> 4;
    int l16  = lane & 15;
    int lrow = wave * 16 + l16;
    short8 af[4];
    #pragma unroll
    for (int kk = 0; kk < 4; ++kk) {
        uint4 v = *(const uint4*)&hA[lrow][(kk * 4 + quad) * 4];
        af[kk] = *(short8*)&v;
    }
    __syncthreads();          // all waves done reading A before hA reused for C
    f32x4 accs[8];
    #pragma unroll
    for (int nt = 0; nt < 8; ++nt) {
        int n = nt * 16 + l16;
        const uint4* Wrow = (const uint4*)(Wt + (size_t)n * FDH);
        f32x4 acc = {0.f, 0.f, 0.f, 0.f};
        #pragma unroll
        for (int kk = 0; kk < 4; ++kk) {
            uint4 wv = Wrow[kk * 4 + quad];
            short8 bf = *(short8*)&wv;
            acc = __builtin_amdgcn_mfma_f32_16x16x32_bf16(af[kk], bf, acc, 0, 0, 0);
        }
        accs[nt] = acc;
    }
    unsigned short* hs = (unsigned short*)hA;   // pitch 136 ushorts (= 68 uints)
    #pragma unroll
    for (int nt = 0; nt < 8; ++nt) {
        #pragma unroll
        for (int reg = 0; reg < 4; ++reg) {
            int row = wave * 16 + quad * 4 + reg;
            hs[row * 136 + nt * 16 + l16] = f2bf(accs[nt][reg]);
        }
    }
    __syncthreads();
    for (int i = threadIdx.x; i < 64 * 32; i += 256) {   // 64 rows x 32 uint2
        int row = i >> 5, q = i & 31;
        int gr = mbase + row;
        if (gr < NN)
            ((uint2*)C)[(size_t)gr * 32 + q] = ((const uint2*)&hs[row * 136])[q];
    }
}

// ---------- fused scan: standalone ----------
__global__ __launch_bounds__(256) void scan_fused(const int* degi, const int* batch,
        int* tsum, float* dinv, int* rowstart, int* cursor, int* gstart) {
    __shared__ int sh[256];
    int b = blockIdx.x, t = threadIdx.x;
    int i = b * 256 + t;
    int d = (i < NN) ? degi[i] : 0;
    if (i < NN) dinv[i] = rsqrtf((float)(d + 1));
    int v = (i < NN) ? d + 1 : 0;
    sh[t] = v;
    __syncthreads();
    for (int off = 1; off < 256; off <<= 1) {
        int a = (t >= off) ? sh[t - off] : 0;
        __syncthreads();
        sh[t] += a;
        __syncthreads();
    }
    int incl = sh[t];
    int total = sh[255];
    if (t == 0) atomicExch(&tsum[b], total);   // publish first; total >= 80 > 0
    int pt = 0;
    for (int j = t; j < b; j += 256) {
        int s;
        do { s = atomicAdd(&tsum[j], 0); } while (s == 0);
        pt += s;
    }
    __syncthreads();
    sh[t] = pt;
    __syncthreads();
    for (int off = 128; off >= 1; off >>= 1) {
        if (t < off) sh[t] += sh[t + off];
        __syncthreads();
    }
    int boff = sh[0];
    if (i < NN) {
        int r = boff + incl - v;
        rowstart[i] = r;
        cursor[i]   = r;
    }
    if (i == 0) rowstart[NN] = EETOT;
    if (i < NN) {
        int is64 = (batch[NN - 1] == 0) ? 1 : 0;
        int bc = is64 ? batch[2 * i] : batch[i];
        if (i == 0) {
            for (int g = 0; g <= bc; ++g) gstart[g] = 0;
        } else {
            int bp = is64 ? batch[2 * (i - 1)] : batch[i - 1];
            for (int g = bp + 1; g <= bc; ++g) gstart[g] = i;
        }
        if (i == NN - 1) {
            for (int g = bc + 1; g <= NG; ++g) gstart[g] = NN;
        }
    }
}

// ---------- binned CSR fill (standalone: cv lines stay L2-resident) ----------
__global__ __launch_bounds__(256) void fill_kernel(const int2* ebsd, const int* bofs,
        const float* dinv, int* cursor, unsigned int* cv) {
    int par = blockIdx.x & 7;        // matches XCD round-robin
    int g   = blockIdx.x >> 3;       // group within parity [0,FPB)
    for (int chunk = g; chunk < NCHK; chunk += FPB) {
        int b0 = bofs[chunk * 8 + par];
        int nedge = NE - chunk * ECHK; if (nedge > ECHK) nedge = ECHK;
        int b1 = (par < 7) ? bofs[chunk * 8 + par + 1] : nedge;
        for (int j = b0 + (int)threadIdx.x; j < b1; j += 256) {
            int2 sd = ebsd[chunk * ECHK + j];
            int pos = atomicAdd(&cursor[sd.y], 1);
            cv[pos] = (unsigned int)sd.x
                    | ((unsigned int)f2bf(dinv[sd.x] * dinv[sd.y]) << 16);
        }
    }
    // self-loops for this parity's node range
    for (int n = par * NPXCD + g * 256 + threadIdx.x; n < (par + 1) * NPXCD;
         n += FPB * 256) {
        int pos = atomicAdd(&cursor[n], 1);
        float di = dinv[n];
        cv[pos] = (unsigned int)n | ((unsigned int)f2bf(di * di) << 16);
    }
}

// ---------- fused: agg layer1 (Phase A) + GEMM2 (Phase B), block = 16 nodes ------
__global__ __launch_bounds__(256) void agg_gemm2(const unsigned int* Hb,
        const unsigned int* cv, const int* rowstart, const float* bias,
        const unsigned int* __restrict__ Wt, unsigned short* __restrict__ C) {
    __shared__ unsigned int hA[16][68];   // 16 rows x 64 uints, +4 pad
    int lane = threadIdx.x & 63;
    int r4   = lane >> 4;
    int c4   = lane & 15;
    int wv   = threadIdx.x >> 6;
    int nb = blockIdx.x * 16;            // NN % 16 == 0
    int n = nb + wv * 4 + r4;
    const uint4* H4 = (const uint4*)Hb;
    int jb = rowstart[n], je = rowstart[n + 1];
    float a0 = 0.f, a1 = 0.f, a2 = 0.f, a3 = 0.f;
    float a4 = 0.f, a5 = 0.f, a6 = 0.f, a7 = 0.f;
    int j = jb;
    for (; j + 7 < je; j += 8) {
        unsigned int rr[8]; uint4 hh[8];
        #pragma unroll
        for (int k = 0; k < 8; ++k) rr[k] = cv[j + k];
        #pragma unroll
        for (int k = 0; k < 8; ++k) hh[k] = H4[(size_t)(rr[k] & 0xFFFFu) * 16 + c4];
        #pragma unroll
        for (int k = 0; k < 8; ++k) {
            float v = bfbits((unsigned short)(rr[k] >> 16));
            a0 += v * bflo(hh[k].x); a1 += v * bfhi(hh[k].x);
            a2 += v * bflo(hh[k].y); a3 += v * bfhi(hh[k].y);
            a4 += v * bflo(hh[k].z); a5 += v * bfhi(hh[k].z);
            a6 += v * bflo(hh[k].w); a7 += v * bfhi(hh[k].w);
        }
    }
    for (; j + 3 < je; j += 4) {
        unsigned int rr[4]; uint4 hh[4];
        #pragma unroll
        for (int k = 0; k < 4; ++k) rr[k] = cv[j + k];
        #pragma unroll
        for (int k = 0; k < 4; ++k) hh[k] = H4[(size_t)(rr[k] & 0xFFFFu) * 16 + c4];
        #pragma unroll
        for (int k = 0; k < 4; ++k) {
            float v = bfbits((unsigned short)(rr[k] >> 16));
            a0 += v * bflo(hh[k].x); a1 += v * bfhi(hh[k].x);
            a2 += v * bflo(hh[k].y); a3 += v * bfhi(hh[k].y);
            a4 += v * bflo(hh[k].z); a5 += v * bfhi(hh[k].z);
            a6 += v * bflo(hh[k].w); a7 += v * bfhi(hh[k].w);
        }
    }
    for (; j < je; ++j) {
        unsigned int r = cv[j];
        uint4 h = H4[(size_t)(r & 0xFFFFu) * 16 + c4];
        float v = bfbits((unsigned short)(r >> 16));
        a0 += v * bflo(h.x); a1 += v * bfhi(h.x);
        a2 += v * bflo(h.y); a3 += v * bfhi(h.y);
        a4 += v * bflo(h.z); a5 += v * bfhi(h.z);
        a6 += v * bflo(h.w); a7 += v * bfhi(h.w);
    }
    a0 = fmaxf(a0 + bias[8 * c4 + 0], 0.f);
    a1 = fmaxf(a1 + bias[8 * c4 + 1], 0.f);
    a2 = fmaxf(a2 + bias[8 * c4 + 2], 0.f);
    a3 = fmaxf(a3 + bias[8 * c4 + 3], 0.f);
    a4 = fmaxf(a4 + bias[8 * c4 + 4], 0.f);
    a5 = fmaxf(a5 + bias[8 * c4 + 5], 0.f);
    a6 = fmaxf(a6 + bias[8 * c4 + 6], 0.f);
    a7 = fmaxf(a7 + bias[8 * c4 + 7], 0.f);
    int lrow = wv * 4 + r4;
    hA[lrow][c4 * 4 + 0] = packbf(a0, a1);
    hA[lrow][c4 * 4 + 1] = packbf(a2, a3);
    hA[lrow][c4 * 4 + 2] = packbf(a4, a5);
    hA[lrow][c4 * 4 + 3] = packbf(a6, a7);
    __syncthreads();
    // ---- Phase B: C[16][128] = hA @ W2t; wave wv handles nt = wv*2, wv*2+1
    int quad = lane >> 4;
    int l16  = lane & 15;
    short8 af[4];
    #pragma unroll
    for (int kk = 0; kk < 4; ++kk) {
        const uint4* p = (const uint4*)&hA[l16][(kk * 4 + quad) * 4];
        uint4 v = *p;
        af[kk] = *(short8*)&v;
    }
    #pragma unroll
    for (int t = 0; t < 2; ++t) {
        int nt = wv * 2 + t;
        int nn2 = nt * 16 + l16;
        const uint4* Wrow = (const uint4*)(Wt + (size_t)nn2 * FDH);
        f32x4 acc = {0.f, 0.f, 0.f, 0.f};
        #pragma unroll
        for (int kk = 0; kk < 4; ++kk) {
            uint4 wvv = Wrow[kk * 4 + quad];
            short8 bf = *(short8*)&wvv;
            acc = __builtin_amdgcn_mfma_f32_16x16x32_bf16(af[kk], bf, acc, 0, 0, 0);
        }
        int row0 = nb + quad * 4;
        #pragma unroll
        for (int reg = 0; reg < 4; ++reg) {
            int r = row0 + reg;
            C[(size_t)r * FD + nt * 16 + l16] = f2bf(acc[reg]);
        }
    }
}

// ---------- CSR aggregation: uint4 gathers, 4 rows/wave, 16 rows/block ----------
__global__ __launch_bounds__(256) void aggregate_kernel(const unsigned int* Hb,
        const unsigned int* cv, const int* rowstart, const float* bias,
        unsigned int* outb) {
    int lane = threadIdx.x & 63;
    int r4   = lane >> 4;            // row within wave 0..3
    int c4   = lane & 15;            // uint4 index within 64-word row
    int wv   = threadIdx.x >> 6;
    int n = blockIdx.x * 16 + wv * 4 + r4;   // NN % 16 == 0
    const uint4* H4 = (const uint4*)Hb;
    int jb = rowstart[n], je = rowstart[n + 1];
    float a0 = 0.f, a1 = 0.f, a2 = 0.f, a3 = 0.f;
    float a4 = 0.f, a5 = 0.f, a6 = 0.f, a7 = 0.f;
    int j = jb;
    for (; j + 7 < je; j += 8) {
        unsigned int rr[8]; uint4 hh[8];
        #pragma unroll
        for (int k = 0; k < 8; ++k) rr[k] = cv[j + k];
        #pragma unroll
        for (int k = 0; k < 8; ++k) hh[k] = H4[(size_t)(rr[k] & 0xFFFFu) * 16 + c4];
        #pragma unroll
        for (int k = 0; k < 8; ++k) {
            float v = bfbits((unsigned short)(rr[k] >> 16));
            a0 += v * bflo(hh[k].x); a1 += v * bfhi(hh[k].x);
            a2 += v * bflo(hh[k].y); a3 += v * bfhi(hh[k].y);
            a4 += v * bflo(hh[k].z); a5 += v * bfhi(hh[k].z);
            a6 += v * bflo(hh[k].w); a7 += v * bfhi(hh[k].w);
        }
    }
    for (; j + 3 < je; j += 4) {
        unsigned int rr[4]; uint4 hh[4];
        #pragma unroll
        for (int k = 0; k < 4; ++k) rr[k] = cv[j + k];
        #pragma unroll
        for (int k = 0; k < 4; ++k) hh[k] = H4[(size_t)(rr[k] & 0xFFFFu) * 16 + c4];
        #pragma unroll
        for (int k = 0; k < 4; ++k) {
            float v = bfbits((unsigned short)(rr[k] >> 16));
            a0 += v * bflo(hh[k].x); a1 += v * bfhi(hh[k].x);
            a2 += v * bflo(hh[k].y); a3 += v * bfhi(hh[k].y);
            a4 += v * bflo(hh[k].z); a5 += v * bfhi(hh[k].z);
            a6 += v * bflo(hh[k].w); a7 += v * bfhi(hh[k].w);
        }
    }
    for (; j < je; ++j) {
        unsigned int r = cv[j];
        uint4 h = H4[(size_t)(r & 0xFFFFu) * 16 + c4];
        float v = bfbits((unsigned short)(r >> 16));
        a0 += v * bflo(h.x); a1 += v * bfhi(h.x);
        a2 += v * bflo(h.y); a3 += v * bfhi(h.y);
        a4 += v * bflo(h.z); a5 += v * bfhi(h.z);
        a6 += v * bflo(h.w); a7 += v * bfhi(h.w);
    }
    a0 = fmaxf(a0 + bias[8 * c4 + 0], 0.f);
    a1 = fmaxf(a1 + bias[8 * c4 + 1], 0.f);
    a2 = fmaxf(a2 + bias[8 * c4 + 2], 0.f);
    a3 = fmaxf(a3 + bias[8 * c4 + 3], 0.f);
    a4 = fmaxf(a4 + bias[8 * c4 + 4], 0.f);
    a5 = fmaxf(a5 + bias[8 * c4 + 5], 0.f);
    a6 = fmaxf(a6 + bias[8 * c4 + 6], 0.f);
    a7 = fmaxf(a7 + bias[8 * c4 + 7], 0.f);
    uint4 out;
    out.x = packbf(a0, a1);
    out.y = packbf(a2, a3);
    out.z = packbf(a4, a5);
    out.w = packbf(a6, a7);
    ((uint4*)outb)[(size_t)n * 16 + c4] = out;
}

// ---------- fused mean-pool + MLP head ----------
__global__ __launch_bounds__(256) void poolhead(const unsigned int* Hb,
        const int* gstart, const float* addf, const float* fc1w, const float* fc1b,
        const float* fc2w, const float* fc2b, const unsigned int* x, void* outp) {
    int g = blockIdx.x;
    int t = threadIdx.x;
    int q = t >> 6, w = t & 63;
    int obf = wave_probe_bf16(x, 64);
    int s = gstart[g], e = gstart[g + 1];
    float a0 = 0.f, a1 = 0.f;
    #pragma unroll 4
    for (int n = s + q; n < e; n += 4) {
        unsigned int h = Hb[(size_t)n * FDH + w];
        a0 += bflo(h);
        a1 += bfhi(h);
    }
    __shared__ float pp[4][FD];
    __shared__ float z[FD + FA];
    __shared__ float h[FD];
    pp[q][2 * w]     = a0;
    pp[q][2 * w + 1] = a1;
    __syncthreads();
    if (t < FD) {
        float cnt = (float)(e - s);
        if (cnt < 1.0f) cnt = 1.0f;
        z[t] = (pp[0][t] + pp[1][t] + pp[2][t] + pp[3][t]) / cnt;
    }
    if (t >= FD && t < FD + FA) z[t] = addf[g * FA + (t - FD)];
    __syncthreads();
    if (t < FD) {
        float acc = fc1b[t];
        #pragma unroll 4
        for (int k = 0; k < FD + FA; ++k)
            acc += z[k] * fc1w[k * FD + t];
        h[t] = fmaxf(acc, 0.f);
    }
    __syncthreads();
    if (t < 2) {
        float o = fc2b[t];
        for (int j = 0; j < FD; ++j) o += h[j] * fc2w[j * 2 + t];
        if (obf) ((unsigned short*)outp)[g * 2 + t] = f2bf(o);
        else     ((float*)outp)[g * 2 + t] = o;
    }
}

extern "C" void kernel_launch(void* const* d_in, const int* in_sizes, int n_in,
                              void* d_out, int out_size, void* d_ws, size_t ws_size,
                              hipStream_t stream) {
    (void)out_size;

    if (n_in != 12) {
        hipLaunchKernelGGL(mark_kernel, dim3(1), dim3(128), 0, stream,
                           (float*)d_out, 2000.0f);
        return;
    }
    const int exp_sizes[12] = {6400000, 1600000, 50000, 4096, 16384, 128,
                               16384, 128, 20480, 128, 256, 2};
    for (int i = 0; i < 12; ++i) {
        if (in_sizes[i] != exp_sizes[i]) {
            hipLaunchKernelGGL(mark_kernel, dim3(1), dim3(128), 0, stream,
                               (float*)d_out, 3000.0f + 100.0f * i);
            return;
        }
    }

    size_t off = 0;
    char* base = (char*)d_ws;
#define WSALLOC(ptr, type, nbytes) \
    type* ptr = (type*)(base + off); off += (((size_t)(nbytes)) + 255) & ~(size_t)255;
    WSALLOC(bufA,  unsigned int, (size_t)NN * FDH * 4)
    WSALLOC(bufB,  unsigned int, (size_t)NN * FDH * 4)
    WSALLOC(dinv,  float, (size_t)NN * 4)
    WSALLOC(degi,  int,   (size_t)NN * 4)
    WSALLOC(tsum,  int,   256 * 4)
    WSALLOC(rowst, int,   (size_t)(NN + 1) * 4)
    WSALLOC(cursor,int,   (size_t)NN * 4)
    WSALLOC(cv,    unsigned int, (size_t)EETOT * 4)
    WSALLOC(gstart,int,   (size_t)(NG + 1) * 4)
    WSALLOC(ebsd,  int2,  (size_t)NCHK * ECHK * 8)
    WSALLOC(bofs,  int,   (size_t)NCHK * 8 * 4)
    WSALLOC(W1t,   unsigned int, (size_t)FD * FDH * 4)
    WSALLOC(W2t,   unsigned int, (size_t)FD * FDH * 4)
    WSALLOC(b1f,   float, FD * 4)
    WSALLOC(b2f,   float, FD * 4)
    WSALLOC(addff, float, (size_t)NG * FA * 4)
    WSALLOC(fc1wf, float, (size_t)(FD + FA) * FD * 4)
    WSALLOC(fc1bf, float, FD * 4)
    WSALLOC(fc2wf, float, FD * 2 * 4)
    WSALLOC(fc2bf, float, 2 * 4)
#undef WSALLOC
    if (ws_size < off) {
        hipLaunchKernelGGL(mark_kernel, dim3(1), dim3(128), 0, stream,
                           (float*)d_out, 1000.0f);
        return;
    }

    const int* ei    = (const int*)d_in[1];
    const int* batch = (const int*)d_in[2];

    hipLaunchKernelGGL(prep_bin, dim3(PREPB + NCHK), dim3(256), 0, stream,
                       d_in[3], d_in[4], d_in[5], d_in[6], d_in[7],
                       d_in[8], d_in[9], d_in[10], d_in[11],
                       W1t, W2t, addff, b1f, b2f, fc1wf, fc1bf,
                       fc2wf, fc2bf, degi, tsum, ei, ebsd, bofs);

    hipLaunchKernelGGL(deg_gemm1, dim3(FILLB + GEMMB), dim3(256), 0, stream,
                       ebsd, bofs, degi,
                       d_in[0], W1t, (unsigned short*)bufA);

    hipLaunchKernelGGL(scan_fused, dim3(NBLK), dim3(256), 0, stream,
                       degi, batch, tsum, dinv, rowst, cursor, gstart);

    hipLaunchKernelGGL(fill_kernel, dim3(FILLB), dim3(256), 0, stream,
                       ebsd, bofs, dinv, cursor, cv);

    // layer 1 aggregate + layer 2 GEMM fused: bufA(H1) -> bufB(H2)
    hipLaunchKernelGGL(agg_gemm2, dim3(NN / 16), dim3(256), 0, stream,
                       bufA, cv, rowst, b1f, W2t, (unsigned short*)bufB);

    // layer 2 aggregate: bufB(H2) -> bufA (relu'd, packed)
    hipLaunchKernelGGL(aggregate_kernel, dim3(NN / 16), dim3(256), 0, stream,
                       bufB, cv, rowst, b2f, bufA);

    hipLaunchKernelGGL(poolhead, dim3(NG), dim3(256), 0, stream,
                       bufA, gstart, addff, fc1wf, fc1bf, fc2wf, fc2bf,
                       (const unsigned int*)d_in[0], d_out);
}